// Round 2
// baseline (311.803 us; speedup 1.0000x reference)
//
#include <hip/hip_runtime.h>
#include <hip/hip_bf16.h>
#include <hip/hip_fp16.h>

#define B_  4
#define S_  2048
#define D_  1024
#define E_  8
#define K2_ 2048   // 2*D

#define CHUNKS 64
#define CLEN   32  // CHUNKS*CLEN == S_

typedef __attribute__((ext_vector_type(8))) short short8;   // 8 bf16 (4 VGPRs)
typedef __attribute__((ext_vector_type(4))) float floatx4;  // 4 fp32 acc

__device__ __forceinline__ void gld16(const void* g, const void* l) {
    __builtin_amdgcn_global_load_lds(
        (const __attribute__((address_space(1))) unsigned int*)g,
        (__attribute__((address_space(3))) unsigned int*)l, 16, 0, 0);
}

// float -> bf16 bits (RNE)
__device__ __forceinline__ unsigned short f2bf(float f) {
    unsigned int u = __float_as_uint(f);
    u += 0x7fffu + ((u >> 16) & 1u);
    return (unsigned short)(u >> 16);
}

// ---------------- 1. RMSNorm (f32 in -> bf16 out), vectorized ----------------
__global__ void rmsnorm_k(const float* __restrict__ in, const float* __restrict__ nw,
                          __hip_bfloat16* __restrict__ x) {
    int b = blockIdx.y, s = blockIdx.x, t = threadIdx.x;
    const float4* row = (const float4*)(in + ((size_t)b * S_ + s) * D_);
    float4 v = row[t];
    float ss = v.x * v.x + v.y * v.y + v.z * v.z + v.w * v.w;
#pragma unroll
    for (int o = 32; o > 0; o >>= 1) ss += __shfl_down(ss, o, 64);
    __shared__ float ls[4];
    if ((t & 63) == 0) ls[t >> 6] = ss;
    __syncthreads();
    float tot = ls[0] + ls[1] + ls[2] + ls[3];
    float rs = rsqrtf(tot * (1.0f / (float)D_) + 1e-6f);
    float4 w = ((const float4*)nw)[t];
    ushort4 o;
    o.x = f2bf(v.x * rs * w.x); o.y = f2bf(v.y * rs * w.y);
    o.z = f2bf(v.z * rs * w.z); o.w = f2bf(v.w * rs * w.w);
    ((ushort4*)(x + ((size_t)b * S_ + s) * D_))[t] = o;
}

// ---------------- 2a. column sums of x over S (router mean) ----------------
__global__ void xsum_k(const __hip_bfloat16* __restrict__ x, float* __restrict__ xs) {
    int d = blockIdx.x * 256 + threadIdx.x;
    int b = blockIdx.y;
    int s0 = blockIdx.z * 128;
    const __hip_bfloat16* p = x + ((size_t)b * S_ + s0) * D_ + d;
    float acc = 0.0f;
#pragma unroll 4
    for (int s = 0; s < 128; s++) { acc += __bfloat162float(*p); p += D_; }
    atomicAdd(&xs[b * D_ + d], acc);
}

// ---------------- 2b. router logits + softmax (+ aux_loss=0) ----------------
__global__ void router_k(const float* __restrict__ xs, const float* __restrict__ rw,
                         const float* __restrict__ rb, float* __restrict__ probs,
                         float* __restrict__ aux) {
    int t = threadIdx.x;
    if (t == 255) *aux = 0.0f;
    int pair = t >> 3, sub = t & 7;
    int b = pair >> 3, e = pair & 7;
    float acc = 0.0f;
#pragma unroll 8
    for (int d = sub; d < D_; d += 8) acc += xs[b * D_ + d] * rw[e * D_ + d];
#pragma unroll
    for (int o = 4; o > 0; o >>= 1) acc += __shfl_down(acc, o, 8);
    __shared__ float lg[32];
    if (sub == 0) lg[pair] = acc * (1.0f / (float)S_) + rb[e];
    __syncthreads();
    if (t < 4) {
        float m = -1e30f;
        for (int e2 = 0; e2 < 8; e2++) m = fmaxf(m, lg[t * 8 + e2]);
        float ssum = 0.0f; float ex[8];
        for (int e2 = 0; e2 < 8; e2++) { ex[e2] = expf(lg[t * 8 + e2] - m); ssum += ex[e2]; }
        for (int e2 = 0; e2 < 8; e2++) probs[t * 8 + e2] = ex[e2] / ssum;
    }
}

// ---------------- 3. mix expert weights (float4 loads, bf16x4 stores) --------
__global__ void mix_k(const float* __restrict__ probs, const float* __restrict__ whg_e,
                      const float* __restrict__ wout_e, __hip_bfloat16* __restrict__ Whg,
                      __hip_bfloat16* __restrict__ Wout) {
    __shared__ float P[32];
    int t = threadIdx.x;
    if (t < 32) P[t] = probs[t];
    __syncthreads();
    size_t i4 = (size_t)blockIdx.x * 256 + t;          // float4 index
    const size_t T1q = (size_t)K2_ * D_ / 4;           // 524288
    const size_t T2q = (size_t)D_ * D_ / 4;            // 262144
    float4 a0 = {0,0,0,0}, a1 = {0,0,0,0}, a2 = {0,0,0,0}, a3 = {0,0,0,0};
    if (i4 < T1q) {
        const float4* src = (const float4*)whg_e;
#pragma unroll
        for (int e = 0; e < 8; e++) {
            float4 wv = src[(size_t)e * T1q + i4];
            float p0 = P[e], p1 = P[8 + e], p2 = P[16 + e], p3 = P[24 + e];
            a0.x += p0 * wv.x; a0.y += p0 * wv.y; a0.z += p0 * wv.z; a0.w += p0 * wv.w;
            a1.x += p1 * wv.x; a1.y += p1 * wv.y; a1.z += p1 * wv.z; a1.w += p1 * wv.w;
            a2.x += p2 * wv.x; a2.y += p2 * wv.y; a2.z += p2 * wv.z; a2.w += p2 * wv.w;
            a3.x += p3 * wv.x; a3.y += p3 * wv.y; a3.z += p3 * wv.z; a3.w += p3 * wv.w;
        }
        ushort4* dst = (ushort4*)Whg;
        ushort4 o;
        o.x = f2bf(a0.x); o.y = f2bf(a0.y); o.z = f2bf(a0.z); o.w = f2bf(a0.w);
        dst[0 * T1q + i4] = o;
        o.x = f2bf(a1.x); o.y = f2bf(a1.y); o.z = f2bf(a1.z); o.w = f2bf(a1.w);
        dst[1 * T1q + i4] = o;
        o.x = f2bf(a2.x); o.y = f2bf(a2.y); o.z = f2bf(a2.z); o.w = f2bf(a2.w);
        dst[2 * T1q + i4] = o;
        o.x = f2bf(a3.x); o.y = f2bf(a3.y); o.z = f2bf(a3.z); o.w = f2bf(a3.w);
        dst[3 * T1q + i4] = o;
    } else {
        size_t j4 = i4 - T1q;
        const float4* src = (const float4*)wout_e;
#pragma unroll
        for (int e = 0; e < 8; e++) {
            float4 wv = src[(size_t)e * T2q + j4];
            float p0 = P[e], p1 = P[8 + e], p2 = P[16 + e], p3 = P[24 + e];
            a0.x += p0 * wv.x; a0.y += p0 * wv.y; a0.z += p0 * wv.z; a0.w += p0 * wv.w;
            a1.x += p1 * wv.x; a1.y += p1 * wv.y; a1.z += p1 * wv.z; a1.w += p1 * wv.w;
            a2.x += p2 * wv.x; a2.y += p2 * wv.y; a2.z += p2 * wv.z; a2.w += p2 * wv.w;
            a3.x += p3 * wv.x; a3.y += p3 * wv.y; a3.z += p3 * wv.z; a3.w += p3 * wv.w;
        }
        ushort4* dst = (ushort4*)Wout;
        ushort4 o;
        o.x = f2bf(a0.x); o.y = f2bf(a0.y); o.z = f2bf(a0.z); o.w = f2bf(a0.w);
        dst[0 * T2q + j4] = o;
        o.x = f2bf(a1.x); o.y = f2bf(a1.y); o.z = f2bf(a1.z); o.w = f2bf(a1.w);
        dst[1 * T2q + j4] = o;
        o.x = f2bf(a2.x); o.y = f2bf(a2.y); o.z = f2bf(a2.z); o.w = f2bf(a2.w);
        dst[2 * T2q + j4] = o;
        o.x = f2bf(a3.x); o.y = f2bf(a3.y); o.z = f2bf(a3.z); o.w = f2bf(a3.w);
        dst[3 * T2q + j4] = o;
    }
}

// ---------------- 4. fused GEMM1 + (c,v) epilogue, 128m x 64n-dual tile ------
// Round-6: m248 minimum-2-phase — ONE barrier per K-step, vmcnt(0) AFTER the
// MFMA cluster (stage loads in flight across the whole compute phase), hoisted
// global staging pointers (+128 B/step), setprio(1) around MFMA.
__global__ __launch_bounds__(256) void gemm_hg_cv(
    const __hip_bfloat16* __restrict__ A, const __hip_bfloat16* __restrict__ Bm,
    __half2* __restrict__ cv) {
    const int K = D_;
    int bz = blockIdx.z;
    A  += (size_t)bz * S_ * D_;
    Bm += (size_t)bz * K2_ * D_;
    __half2* CV = cv + (size_t)bz * S_ * D_;
    int m0 = blockIdx.y * 128, n0 = blockIdx.x * 64;
    __shared__ __hip_bfloat16 lA[2][128][64];
    __shared__ __hip_bfloat16 lBh[2][64][64];
    __shared__ __hip_bfloat16 lBg[2][64][64];
    int t = threadIdx.x;
    int w = t >> 6, lane = t & 63;
    int lm = lane & 15, quad = lane >> 4;
    int wr = w >> 1, wc = w & 1;             // wave tile: 64 m x 32 n (dual h/g)
    floatx4 acch[4][2] = {};
    floatx4 accg[4][2] = {};
    int srow = lane >> 3;                    // 0..7
    int swzb = ((lane & 7) ^ srow) * 16;     // swizzled source byte-chunk
    int pb = (quad ^ (lm & 7)) * 16;         // kk=0 read byte-chunk; kk=32 = pb^64

    const __hip_bfloat16* Bh = Bm;                    // hidden rows 0..1023
    const __hip_bfloat16* Bg = Bm + (size_t)D_ * K;   // gate rows 1024..2047

    // hoisted global staging pointers (advance +128 B per K-step)
    const char* pA[4]; const char* pBhp[2]; const char* pBgp[2];
#pragma unroll
    for (int it = 0; it < 4; it++)
        pA[it] = (const char*)(A + (size_t)(m0 + (w * 4 + it) * 8 + srow) * K) + swzb;
#pragma unroll
    for (int it = 0; it < 2; it++) {
        pBhp[it] = (const char*)(Bh + (size_t)(n0 + (w * 2 + it) * 8 + srow) * K) + swzb;
        pBgp[it] = (const char*)(Bg + (size_t)(n0 + (w * 2 + it) * 8 + srow) * K) + swzb;
    }

    auto stage = [&](int bb) {
#pragma unroll
        for (int it = 0; it < 4; it++) {
            gld16(pA[it], &lA[bb][(w * 4 + it) * 8][0]);
            pA[it] += 128;
        }
#pragma unroll
        for (int it = 0; it < 2; it++) {
            gld16(pBhp[it], &lBh[bb][(w * 2 + it) * 8][0]); pBhp[it] += 128;
            gld16(pBgp[it], &lBg[bb][(w * 2 + it) * 8][0]); pBgp[it] += 128;
        }
    };

    stage(0);
    asm volatile("s_waitcnt vmcnt(0)" ::: "memory");
    __builtin_amdgcn_s_barrier();
    int cur = 0;
    for (int k0 = 0; k0 < K; k0 += 64) {
        bool pre = (k0 + 64 < K);
        // kk=0 fragment reads BEFORE the stage issue (no alias-wait exposure)
        short8 af0[4], bh0[2], bg0[2];
#pragma unroll
        for (int i = 0; i < 4; i++)
            af0[i] = *(const short8*)((const char*)&lA[cur][wr * 64 + i * 16 + lm][0] + pb);
#pragma unroll
        for (int j = 0; j < 2; j++) {
            bh0[j] = *(const short8*)((const char*)&lBh[cur][wc * 32 + j * 16 + lm][0] + pb);
            bg0[j] = *(const short8*)((const char*)&lBg[cur][wc * 32 + j * 16 + lm][0] + pb);
        }
        if (pre) stage(cur ^ 1);             // next tile in flight across compute
        __builtin_amdgcn_s_setprio(1);
#pragma unroll
        for (int i = 0; i < 4; i++)
#pragma unroll
            for (int j = 0; j < 2; j++) {
                acch[i][j] = __builtin_amdgcn_mfma_f32_16x16x32_bf16(
                    af0[i], bh0[j], acch[i][j], 0, 0, 0);
                accg[i][j] = __builtin_amdgcn_mfma_f32_16x16x32_bf16(
                    af0[i], bg0[j], accg[i][j], 0, 0, 0);
            }
        // kk=32
        short8 af1[4], bh1[2], bg1[2];
#pragma unroll
        for (int i = 0; i < 4; i++)
            af1[i] = *(const short8*)((const char*)&lA[cur][wr * 64 + i * 16 + lm][0] + (pb ^ 64));
#pragma unroll
        for (int j = 0; j < 2; j++) {
            bh1[j] = *(const short8*)((const char*)&lBh[cur][wc * 32 + j * 16 + lm][0] + (pb ^ 64));
            bg1[j] = *(const short8*)((const char*)&lBg[cur][wc * 32 + j * 16 + lm][0] + (pb ^ 64));
        }
#pragma unroll
        for (int i = 0; i < 4; i++)
#pragma unroll
            for (int j = 0; j < 2; j++) {
                acch[i][j] = __builtin_amdgcn_mfma_f32_16x16x32_bf16(
                    af1[i], bh1[j], acch[i][j], 0, 0, 0);
                accg[i][j] = __builtin_amdgcn_mfma_f32_16x16x32_bf16(
                    af1[i], bg1[j], accg[i][j], 0, 0, 0);
            }
        __builtin_amdgcn_s_setprio(0);
        if (pre) {
            asm volatile("s_waitcnt vmcnt(0)" ::: "memory");  // next tile landed
            __builtin_amdgcn_s_barrier();                     // one barrier/step
        }
        cur ^= 1;
    }
#pragma unroll
    for (int i = 0; i < 4; i++) {
#pragma unroll
        for (int j = 0; j < 2; j++) {
#pragma unroll
            for (int r = 0; r < 4; r++) {
                int m = m0 + wr * 64 + i * 16 + quad * 4 + r;
                int n = n0 + wc * 32 + j * 16 + lm;
                float hid = acch[i][j][r];
                float g   = accg[i][j][r];
                float eg  = expf(g);
                float c   = 1.0f / (1.0f + eg);        // sigmoid(-g)
                float sg  = 1.0f - c;                  // sigmoid(g)
                float gfn = (hid >= 0.0f) ? (hid + 0.5f)
                                          : (1.0f / (1.0f + expf(-hid)));
                CV[(size_t)m * D_ + n] = __floats2half2_rn(c, sg * gfn);
            }
        }
    }
}

// ---------------- 6. bf16 MFMA GEMM, C = A * B^T (+R), XOR-swizzled LDS ----
// Round-6: same m248 minimum-2-phase conversion + hoisted pointers.
#define TM 128
#define TN 128
#define TBK 64
__global__ __launch_bounds__(256) void gemm_bf16_bt(
    const __hip_bfloat16* __restrict__ A, const __hip_bfloat16* __restrict__ Bm,
    float* __restrict__ C, const float* __restrict__ R,
    int M, int N, int K, size_t sa, size_t sb, size_t sc, size_t sr) {
    int bz = blockIdx.z;
    A += (size_t)bz * sa; Bm += (size_t)bz * sb; C += (size_t)bz * sc;
    if (R) R += (size_t)bz * sr;
    int m0 = blockIdx.y * TM, n0 = blockIdx.x * TN;
    __shared__ __hip_bfloat16 lA[2][TM][TBK];
    __shared__ __hip_bfloat16 lB[2][TN][TBK];
    int t = threadIdx.x;
    int w = t >> 6, lane = t & 63;
    int lm = lane & 15, quad = lane >> 4;
    int wr = w >> 1, wc = w & 1;
    floatx4 acc[4][4] = {};
    int srow = lane >> 3;
    int swzb = ((lane & 7) ^ srow) * 16;
    int pb = (quad ^ (lm & 7)) * 16;

    const char* pA[4]; const char* pB[4];
#pragma unroll
    for (int it = 0; it < 4; it++) {
        pA[it] = (const char*)(A + (size_t)(m0 + (w * 4 + it) * 8 + srow) * K) + swzb;
        pB[it] = (const char*)(Bm + (size_t)(n0 + (w * 4 + it) * 8 + srow) * K) + swzb;
    }

    auto stage = [&](int bb) {
#pragma unroll
        for (int it = 0; it < 4; it++) {
            gld16(pA[it], &lA[bb][(w * 4 + it) * 8][0]); pA[it] += 128;
            gld16(pB[it], &lB[bb][(w * 4 + it) * 8][0]); pB[it] += 128;
        }
    };

    stage(0);
    asm volatile("s_waitcnt vmcnt(0)" ::: "memory");
    __builtin_amdgcn_s_barrier();
    int cur = 0;
    for (int k0 = 0; k0 < K; k0 += TBK) {
        bool pre = (k0 + TBK < K);
        short8 af0[4], bf0[4];
#pragma unroll
        for (int i = 0; i < 4; i++)
            af0[i] = *(const short8*)((const char*)&lA[cur][wr * 64 + i * 16 + lm][0] + pb);
#pragma unroll
        for (int j = 0; j < 4; j++)
            bf0[j] = *(const short8*)((const char*)&lB[cur][wc * 64 + j * 16 + lm][0] + pb);
        if (pre) stage(cur ^ 1);
        __builtin_amdgcn_s_setprio(1);
#pragma unroll
        for (int i = 0; i < 4; i++)
#pragma unroll
            for (int j = 0; j < 4; j++)
                acc[i][j] = __builtin_amdgcn_mfma_f32_16x16x32_bf16(
                    af0[i], bf0[j], acc[i][j], 0, 0, 0);
        short8 af1[4], bf1[4];
#pragma unroll
        for (int i = 0; i < 4; i++)
            af1[i] = *(const short8*)((const char*)&lA[cur][wr * 64 + i * 16 + lm][0] + (pb ^ 64));
#pragma unroll
        for (int j = 0; j < 4; j++)
            bf1[j] = *(const short8*)((const char*)&lB[cur][wc * 64 + j * 16 + lm][0] + (pb ^ 64));
#pragma unroll
        for (int i = 0; i < 4; i++)
#pragma unroll
            for (int j = 0; j < 4; j++)
                acc[i][j] = __builtin_amdgcn_mfma_f32_16x16x32_bf16(
                    af1[i], bf1[j], acc[i][j], 0, 0, 0);
        __builtin_amdgcn_s_setprio(0);
        if (pre) {
            asm volatile("s_waitcnt vmcnt(0)" ::: "memory");
            __builtin_amdgcn_s_barrier();
        }
        cur ^= 1;
    }
#pragma unroll
    for (int i = 0; i < 4; i++) {
#pragma unroll
        for (int j = 0; j < 4; j++) {
#pragma unroll
            for (int r = 0; r < 4; r++) {
                int m = m0 + wr * 64 + i * 16 + quad * 4 + r;
                int n = n0 + wc * 64 + j * 16 + lm;
                float v = acc[i][j][r];
                if (R) v += R[(size_t)m * N + n];
                C[(size_t)m * N + n] = v;
            }
        }
    }
}

// ---------------- 5. chunked LINEAR scan over half2 cv (4 d's per thread) ----
// phase A: per-chunk composition. grid (CHUNKS, B_), block 256.
__global__ void scanA_k(const __half2* __restrict__ cv, float* __restrict__ Cc,
                        float* __restrict__ Vc) {
    int c = blockIdx.x, b = blockIdx.y, t = threadIdx.x;
    const float4* p = (const float4*)(cv + (size_t)(b * S_ + c * CLEN) * D_) + t;
    float P0 = 1, P1 = 1, P2 = 1, P3 = 1;
    float V0 = 0, V1 = 0, V2 = 0, V3 = 0;
#pragma unroll 4
    for (int s = 0; s < CLEN; s++) {
        float4 raw = p[(size_t)s * (D_ / 4)];
        const __half2* e = (const __half2*)&raw;
        float c0 = __low2float(e[0]), v0 = __high2float(e[0]);
        float c1 = __low2float(e[1]), v1 = __high2float(e[1]);
        float c2 = __low2float(e[2]), v2 = __high2float(e[2]);
        float c3 = __low2float(e[3]), v3 = __high2float(e[3]);
        P0 *= c0; V0 = fmaf(c0, V0, v0);
        P1 *= c1; V1 = fmaf(c1, V1, v1);
        P2 *= c2; V2 = fmaf(c2, V2, v2);
        P3 *= c3; V3 = fmaf(c3, V3, v3);
    }
    size_t q = ((size_t)(b * CHUNKS + c)) * (D_ / 4) + t;
    ((float4*)Cc)[q] = make_float4(P0, P1, P2, P3);
    ((float4*)Vc)[q] = make_float4(V0, V1, V2, V3);
}

// phase C with inline lookback over Cc/Vc (L2-hot). grid (CHUNKS, B_), 256.
__global__ void scanC_k(const __half2* __restrict__ cv, const float* __restrict__ Cc,
                        const float* __restrict__ Vc,
                        __hip_bfloat16* __restrict__ hout, float* __restrict__ ns) {
    int c = blockIdx.x, b = blockIdx.y, t = threadIdx.x;
    float h0 = 0, h1 = 0, h2 = 0, h3 = 0;
#pragma unroll 4
    for (int cc = 0; cc < c; cc++) {
        size_t q = ((size_t)(b * CHUNKS + cc)) * (D_ / 4) + t;
        float4 C4 = ((const float4*)Cc)[q];
        float4 V4 = ((const float4*)Vc)[q];
        h0 = fmaf(C4.x, h0, V4.x); h1 = fmaf(C4.y, h1, V4.y);
        h2 = fmaf(C4.z, h2, V4.z); h3 = fmaf(C4.w, h3, V4.w);
    }
    const float4* p = (const float4*)(cv + (size_t)(b * S_ + c * CLEN) * D_) + t;
    ushort4* hq = (ushort4*)(hout + (size_t)(b * S_ + c * CLEN) * D_) + t;
#pragma unroll 4
    for (int s = 0; s < CLEN; s++) {
        float4 raw = p[(size_t)s * (D_ / 4)];
        const __half2* e = (const __half2*)&raw;
        h0 = fmaf(__low2float(e[0]), h0, __high2float(e[0]));
        h1 = fmaf(__low2float(e[1]), h1, __high2float(e[1]));
        h2 = fmaf(__low2float(e[2]), h2, __high2float(e[2]));
        h3 = fmaf(__low2float(e[3]), h3, __high2float(e[3]));
        ushort4 o;
        o.x = f2bf(h0); o.y = f2bf(h1); o.z = f2bf(h2); o.w = f2bf(h3);
        hq[(size_t)s * (D_ / 4)] = o;
    }
    if (c == CHUNKS - 1)
        ((float4*)(ns + (size_t)b * D_))[t] = make_float4(h0, h1, h2, h3);
}

// ---------------- launcher ----------------
extern "C" void kernel_launch(void* const* d_in, const int* in_sizes, int n_in,
                              void* d_out_v, int out_size, void* d_ws, size_t ws_size,
                              hipStream_t stream) {
    const float* inputs = (const float*)d_in[0];
    const float* nw     = (const float*)d_in[1];
    const float* rw     = (const float*)d_in[2];
    const float* rb     = (const float*)d_in[3];
    const float* whg_e  = (const float*)d_in[4];
    const float* wout_e = (const float*)d_in[5];
    float* out = (float*)d_out_v;

    float* ws = (float*)d_ws;
    __half2*        cv      = (__half2*)ws;                     // 8388608 half2 (33.5 MB)
    __hip_bfloat16* x_bf    = (__hip_bfloat16*)(ws + 8388608);  // 8388608 bf16
    __hip_bfloat16* h_bf    = (__hip_bfloat16*)(ws + 12582912); // 8388608 bf16
    __hip_bfloat16* Whg_bf  = (__hip_bfloat16*)(ws + 16777216); // 8388608 bf16
    __hip_bfloat16* Wout_bf = (__hip_bfloat16*)(ws + 20971520); // 4194304 bf16
    float* xsum  = ws + 23068672;  // 4096
    float* probs = ws + 23072768;  // 32
    float* Cc    = ws + 23072800;  // 262144
    float* Vc    = ws + 23334944;  // 262144

    hipMemsetAsync(xsum, 0, (size_t)B_ * D_ * sizeof(float), stream);

    rmsnorm_k<<<dim3(S_, B_), 256, 0, stream>>>(inputs, nw, x_bf);
    xsum_k<<<dim3(D_ / 256, B_, 16), 256, 0, stream>>>(x_bf, xsum);
    router_k<<<1, 256, 0, stream>>>(xsum, rw, rb, probs,
                                    out + (size_t)B_ * S_ * D_ + (size_t)B_ * D_);
    mix_k<<<3072, 256, 0, stream>>>(probs, whg_e, wout_e, Whg_bf, Wout_bf);

    // fused GEMM1 + (c,v): 128m x 64n-dual tile, single-barrier 2-phase
    gemm_hg_cv<<<dim3(D_ / 64, S_ / 128, B_), 256, 0, stream>>>(x_bf, Whg_bf, cv);

    scanA_k<<<dim3(CHUNKS, B_), 256, 0, stream>>>(cv, Cc, Vc);
    scanC_k<<<dim3(CHUNKS, B_), 256, 0, stream>>>(
        cv, Cc, Vc, h_bf, out + (size_t)B_ * S_ * D_);

    // out[b] = h[b] (2048x1024) * Wout[b]^T + inputs[b]
    gemm_bf16_bt<<<dim3(D_ / TN, S_ / TM, B_), 256, 0, stream>>>(
        h_bf, Wout_bf, out, inputs, S_, D_, D_,
        (size_t)S_ * D_, (size_t)D_ * D_, (size_t)S_ * D_, (size_t)S_ * D_);
}

// Round 3
// 308.450 us; speedup vs baseline: 1.0109x; 1.0109x over previous
//
#include <hip/hip_runtime.h>
#include <hip/hip_bf16.h>
#include <hip/hip_fp16.h>

#define B_  4
#define S_  2048
#define D_  1024
#define E_  8
#define K2_ 2048   // 2*D

#define CHUNKS 64
#define CLEN   32  // CHUNKS*CLEN == S_

typedef __attribute__((ext_vector_type(8))) short short8;   // 8 bf16 (4 VGPRs)
typedef __attribute__((ext_vector_type(4))) float floatx4;  // 4 fp32 acc

__device__ __forceinline__ void gld16(const void* g, const void* l) {
    __builtin_amdgcn_global_load_lds(
        (const __attribute__((address_space(1))) unsigned int*)g,
        (__attribute__((address_space(3))) unsigned int*)l, 16, 0, 0);
}

// float -> bf16 bits (RNE)
__device__ __forceinline__ unsigned short f2bf(float f) {
    unsigned int u = __float_as_uint(f);
    u += 0x7fffu + ((u >> 16) & 1u);
    return (unsigned short)(u >> 16);
}

// ---------------- 1. RMSNorm (f32 in -> bf16 out), vectorized ----------------
__global__ void rmsnorm_k(const float* __restrict__ in, const float* __restrict__ nw,
                          __hip_bfloat16* __restrict__ x) {
    int b = blockIdx.y, s = blockIdx.x, t = threadIdx.x;
    const float4* row = (const float4*)(in + ((size_t)b * S_ + s) * D_);
    float4 v = row[t];
    float ss = v.x * v.x + v.y * v.y + v.z * v.z + v.w * v.w;
#pragma unroll
    for (int o = 32; o > 0; o >>= 1) ss += __shfl_down(ss, o, 64);
    __shared__ float ls[4];
    if ((t & 63) == 0) ls[t >> 6] = ss;
    __syncthreads();
    float tot = ls[0] + ls[1] + ls[2] + ls[3];
    float rs = rsqrtf(tot * (1.0f / (float)D_) + 1e-6f);
    float4 w = ((const float4*)nw)[t];
    ushort4 o;
    o.x = f2bf(v.x * rs * w.x); o.y = f2bf(v.y * rs * w.y);
    o.z = f2bf(v.z * rs * w.z); o.w = f2bf(v.w * rs * w.w);
    ((ushort4*)(x + ((size_t)b * S_ + s) * D_))[t] = o;
}

// ---------------- 2a. column sums of x over S (router mean) ----------------
__global__ void xsum_k(const __hip_bfloat16* __restrict__ x, float* __restrict__ xs) {
    int d = blockIdx.x * 256 + threadIdx.x;
    int b = blockIdx.y;
    int s0 = blockIdx.z * 128;
    const __hip_bfloat16* p = x + ((size_t)b * S_ + s0) * D_ + d;
    float acc = 0.0f;
#pragma unroll 4
    for (int s = 0; s < 128; s++) { acc += __bfloat162float(*p); p += D_; }
    atomicAdd(&xs[b * D_ + d], acc);
}

// ---------------- 2b. router logits + softmax (+ aux_loss=0) ----------------
__global__ void router_k(const float* __restrict__ xs, const float* __restrict__ rw,
                         const float* __restrict__ rb, float* __restrict__ probs,
                         float* __restrict__ aux) {
    int t = threadIdx.x;
    if (t == 255) *aux = 0.0f;
    int pair = t >> 3, sub = t & 7;
    int b = pair >> 3, e = pair & 7;
    float acc = 0.0f;
#pragma unroll 8
    for (int d = sub; d < D_; d += 8) acc += xs[b * D_ + d] * rw[e * D_ + d];
#pragma unroll
    for (int o = 4; o > 0; o >>= 1) acc += __shfl_down(acc, o, 8);
    __shared__ float lg[32];
    if (sub == 0) lg[pair] = acc * (1.0f / (float)S_) + rb[e];
    __syncthreads();
    if (t < 4) {
        float m = -1e30f;
        for (int e2 = 0; e2 < 8; e2++) m = fmaxf(m, lg[t * 8 + e2]);
        float ssum = 0.0f; float ex[8];
        for (int e2 = 0; e2 < 8; e2++) { ex[e2] = expf(lg[t * 8 + e2] - m); ssum += ex[e2]; }
        for (int e2 = 0; e2 < 8; e2++) probs[t * 8 + e2] = ex[e2] / ssum;
    }
}

// ---------------- 3. mix expert weights (float4 loads, bf16x4 stores) --------
__global__ void mix_k(const float* __restrict__ probs, const float* __restrict__ whg_e,
                      const float* __restrict__ wout_e, __hip_bfloat16* __restrict__ Whg,
                      __hip_bfloat16* __restrict__ Wout) {
    __shared__ float P[32];
    int t = threadIdx.x;
    if (t < 32) P[t] = probs[t];
    __syncthreads();
    size_t i4 = (size_t)blockIdx.x * 256 + t;          // float4 index
    const size_t T1q = (size_t)K2_ * D_ / 4;           // 524288
    const size_t T2q = (size_t)D_ * D_ / 4;            // 262144
    float4 a0 = {0,0,0,0}, a1 = {0,0,0,0}, a2 = {0,0,0,0}, a3 = {0,0,0,0};
    if (i4 < T1q) {
        const float4* src = (const float4*)whg_e;
#pragma unroll
        for (int e = 0; e < 8; e++) {
            float4 wv = src[(size_t)e * T1q + i4];
            float p0 = P[e], p1 = P[8 + e], p2 = P[16 + e], p3 = P[24 + e];
            a0.x += p0 * wv.x; a0.y += p0 * wv.y; a0.z += p0 * wv.z; a0.w += p0 * wv.w;
            a1.x += p1 * wv.x; a1.y += p1 * wv.y; a1.z += p1 * wv.z; a1.w += p1 * wv.w;
            a2.x += p2 * wv.x; a2.y += p2 * wv.y; a2.z += p2 * wv.z; a2.w += p2 * wv.w;
            a3.x += p3 * wv.x; a3.y += p3 * wv.y; a3.z += p3 * wv.z; a3.w += p3 * wv.w;
        }
        ushort4* dst = (ushort4*)Whg;
        ushort4 o;
        o.x = f2bf(a0.x); o.y = f2bf(a0.y); o.z = f2bf(a0.z); o.w = f2bf(a0.w);
        dst[0 * T1q + i4] = o;
        o.x = f2bf(a1.x); o.y = f2bf(a1.y); o.z = f2bf(a1.z); o.w = f2bf(a1.w);
        dst[1 * T1q + i4] = o;
        o.x = f2bf(a2.x); o.y = f2bf(a2.y); o.z = f2bf(a2.z); o.w = f2bf(a2.w);
        dst[2 * T1q + i4] = o;
        o.x = f2bf(a3.x); o.y = f2bf(a3.y); o.z = f2bf(a3.z); o.w = f2bf(a3.w);
        dst[3 * T1q + i4] = o;
    } else {
        size_t j4 = i4 - T1q;
        const float4* src = (const float4*)wout_e;
#pragma unroll
        for (int e = 0; e < 8; e++) {
            float4 wv = src[(size_t)e * T2q + j4];
            float p0 = P[e], p1 = P[8 + e], p2 = P[16 + e], p3 = P[24 + e];
            a0.x += p0 * wv.x; a0.y += p0 * wv.y; a0.z += p0 * wv.z; a0.w += p0 * wv.w;
            a1.x += p1 * wv.x; a1.y += p1 * wv.y; a1.z += p1 * wv.z; a1.w += p1 * wv.w;
            a2.x += p2 * wv.x; a2.y += p2 * wv.y; a2.z += p2 * wv.z; a2.w += p2 * wv.w;
            a3.x += p3 * wv.x; a3.y += p3 * wv.y; a3.z += p3 * wv.z; a3.w += p3 * wv.w;
        }
        ushort4* dst = (ushort4*)Wout;
        ushort4 o;
        o.x = f2bf(a0.x); o.y = f2bf(a0.y); o.z = f2bf(a0.z); o.w = f2bf(a0.w);
        dst[0 * T2q + j4] = o;
        o.x = f2bf(a1.x); o.y = f2bf(a1.y); o.z = f2bf(a1.z); o.w = f2bf(a1.w);
        dst[1 * T2q + j4] = o;
        o.x = f2bf(a2.x); o.y = f2bf(a2.y); o.z = f2bf(a2.z); o.w = f2bf(a2.w);
        dst[2 * T2q + j4] = o;
        o.x = f2bf(a3.x); o.y = f2bf(a3.y); o.z = f2bf(a3.z); o.w = f2bf(a3.w);
        dst[3 * T2q + j4] = o;
    }
}

// ---------------- 4. fused GEMM1 + (c,v) epilogue, 128m x 64n-dual tile ------
// Round-7: R1 sync structure restored (stage -> vmcnt(8) -> barrier -> compute
// -> lgkmcnt(0) -> barrier; measured 58.5us) + hoisted staging pointers +
// bijective XCD-chunk block swizzle + setprio around MFMA.
__global__ __launch_bounds__(256) void gemm_hg_cv(
    const __hip_bfloat16* __restrict__ A, const __hip_bfloat16* __restrict__ Bm,
    __half2* __restrict__ cv) {
    const int K = D_;
    int bz = blockIdx.z;
    A  += (size_t)bz * S_ * D_;
    Bm += (size_t)bz * K2_ * D_;
    __half2* CV = cv + (size_t)bz * S_ * D_;
    // XCD-chunk swizzle: 256 tiles (16m x 16n), nwg%8==0 -> xcd*32 + id/8.
    // Each XCD gets 2 contiguous m-rows (shared A panels, L2-local).
    int id = blockIdx.x;
    int sw = (id & 7) * 32 + (id >> 3);
    int m0 = (sw >> 4) * 128, n0 = (sw & 15) * 64;
    __shared__ __hip_bfloat16 lA[2][128][64];
    __shared__ __hip_bfloat16 lBh[2][64][64];
    __shared__ __hip_bfloat16 lBg[2][64][64];
    int t = threadIdx.x;
    int w = t >> 6, lane = t & 63;
    int lm = lane & 15, quad = lane >> 4;
    int wr = w >> 1, wc = w & 1;             // wave tile: 64 m x 32 n (dual h/g)
    floatx4 acch[4][2] = {};
    floatx4 accg[4][2] = {};
    int srow = lane >> 3;                    // 0..7
    int swzb = ((lane & 7) ^ srow) * 16;     // swizzled source byte-chunk

    const __hip_bfloat16* Bh = Bm;                    // hidden rows 0..1023
    const __hip_bfloat16* Bg = Bm + (size_t)D_ * K;   // gate rows 1024..2047

    // hoisted global staging pointers (advance +128 B per K-step)
    const char* pA[4]; const char* pBhp[2]; const char* pBgp[2];
#pragma unroll
    for (int it = 0; it < 4; it++)
        pA[it] = (const char*)(A + (size_t)(m0 + (w * 4 + it) * 8 + srow) * K) + swzb;
#pragma unroll
    for (int it = 0; it < 2; it++) {
        pBhp[it] = (const char*)(Bh + (size_t)(n0 + (w * 2 + it) * 8 + srow) * K) + swzb;
        pBgp[it] = (const char*)(Bg + (size_t)(n0 + (w * 2 + it) * 8 + srow) * K) + swzb;
    }

    auto stage = [&](int bb) {
#pragma unroll
        for (int it = 0; it < 4; it++) {
            gld16(pA[it], &lA[bb][(w * 4 + it) * 8][0]);
            pA[it] += 128;
        }
#pragma unroll
        for (int it = 0; it < 2; it++) {
            gld16(pBhp[it], &lBh[bb][(w * 2 + it) * 8][0]); pBhp[it] += 128;
            gld16(pBgp[it], &lBg[bb][(w * 2 + it) * 8][0]); pBgp[it] += 128;
        }
    };

    stage(0);
    int cur = 0;
    for (int k0 = 0; k0 < K; k0 += 64) {
        if (k0 + 64 < K) {
            stage(cur ^ 1);                                   // next tile in flight
            asm volatile("s_waitcnt vmcnt(8)" ::: "memory");  // only tile-t's done
        } else {
            asm volatile("s_waitcnt vmcnt(0)" ::: "memory");
        }
        __builtin_amdgcn_s_barrier();                         // tile t visible
#pragma unroll
        for (int kk = 0; kk < 64; kk += 32) {
            short8 af[4], bh[2], bg[2];
            int p = (((kk >> 3) + quad) ^ (lm & 7)) * 8;
#pragma unroll
            for (int i = 0; i < 4; i++)
                af[i] = *(const short8*)(&lA[cur][wr * 64 + i * 16 + lm][p]);
#pragma unroll
            for (int j = 0; j < 2; j++) {
                bh[j] = *(const short8*)(&lBh[cur][wc * 32 + j * 16 + lm][p]);
                bg[j] = *(const short8*)(&lBg[cur][wc * 32 + j * 16 + lm][p]);
            }
            __builtin_amdgcn_s_setprio(1);
#pragma unroll
            for (int i = 0; i < 4; i++)
#pragma unroll
                for (int j = 0; j < 2; j++) {
                    acch[i][j] = __builtin_amdgcn_mfma_f32_16x16x32_bf16(
                        af[i], bh[j], acch[i][j], 0, 0, 0);
                    accg[i][j] = __builtin_amdgcn_mfma_f32_16x16x32_bf16(
                        af[i], bg[j], accg[i][j], 0, 0, 0);
                }
            __builtin_amdgcn_s_setprio(0);
        }
        asm volatile("s_waitcnt lgkmcnt(0)" ::: "memory");    // buf reads retired
        __builtin_amdgcn_s_barrier();                         // safe to overwrite
        cur ^= 1;
    }
#pragma unroll
    for (int i = 0; i < 4; i++) {
#pragma unroll
        for (int j = 0; j < 2; j++) {
#pragma unroll
            for (int r = 0; r < 4; r++) {
                int m = m0 + wr * 64 + i * 16 + quad * 4 + r;
                int n = n0 + wc * 32 + j * 16 + lm;
                float hid = acch[i][j][r];
                float g   = accg[i][j][r];
                float eg  = expf(g);
                float c   = 1.0f / (1.0f + eg);        // sigmoid(-g)
                float sg  = 1.0f - c;                  // sigmoid(g)
                float gfn = (hid >= 0.0f) ? (hid + 0.5f)
                                          : (1.0f / (1.0f + expf(-hid)));
                CV[(size_t)m * D_ + n] = __floats2half2_rn(c, sg * gfn);
            }
        }
    }
}

// ---------------- 6. bf16 MFMA GEMM, C = A * B^T (+R), XOR-swizzled LDS ----
// Round-7: R1 sync structure + hoisted pointers + XCD swizzle (128 tiles: 16m x 8n).
#define TM 128
#define TN 128
#define TBK 64
__global__ __launch_bounds__(256) void gemm_bf16_bt(
    const __hip_bfloat16* __restrict__ A, const __hip_bfloat16* __restrict__ Bm,
    float* __restrict__ C, const float* __restrict__ R,
    int M, int N, int K, size_t sa, size_t sb, size_t sc, size_t sr) {
    int bz = blockIdx.z;
    A += (size_t)bz * sa; Bm += (size_t)bz * sb; C += (size_t)bz * sc;
    if (R) R += (size_t)bz * sr;
    // 128 tiles (16m x 8n): xcd*16 + id/8 (bijective, 128%8==0)
    int id = blockIdx.x;
    int sw = (id & 7) * 16 + (id >> 3);
    int m0 = (sw >> 3) * TM, n0 = (sw & 7) * TN;
    __shared__ __hip_bfloat16 lA[2][TM][TBK];
    __shared__ __hip_bfloat16 lB[2][TN][TBK];
    int t = threadIdx.x;
    int w = t >> 6, lane = t & 63;
    int lm = lane & 15, quad = lane >> 4;
    int wr = w >> 1, wc = w & 1;
    floatx4 acc[4][4] = {};
    int srow = lane >> 3;
    int swzb = ((lane & 7) ^ srow) * 16;

    const char* pA[4]; const char* pB[4];
#pragma unroll
    for (int it = 0; it < 4; it++) {
        pA[it] = (const char*)(A + (size_t)(m0 + (w * 4 + it) * 8 + srow) * K) + swzb;
        pB[it] = (const char*)(Bm + (size_t)(n0 + (w * 4 + it) * 8 + srow) * K) + swzb;
    }

    auto stage = [&](int bb) {
#pragma unroll
        for (int it = 0; it < 4; it++) {
            gld16(pA[it], &lA[bb][(w * 4 + it) * 8][0]); pA[it] += 128;
            gld16(pB[it], &lB[bb][(w * 4 + it) * 8][0]); pB[it] += 128;
        }
    };

    stage(0);
    int cur = 0;
    for (int k0 = 0; k0 < K; k0 += TBK) {
        if (k0 + TBK < K) {
            stage(cur ^ 1);
            asm volatile("s_waitcnt vmcnt(8)" ::: "memory");
        } else {
            asm volatile("s_waitcnt vmcnt(0)" ::: "memory");
        }
        __builtin_amdgcn_s_barrier();
#pragma unroll
        for (int kk = 0; kk < TBK; kk += 32) {
            short8 af[4], bf[4];
            int p = (((kk >> 3) + quad) ^ (lm & 7)) * 8;
#pragma unroll
            for (int i = 0; i < 4; i++)
                af[i] = *(const short8*)(&lA[cur][wr * 64 + i * 16 + lm][p]);
#pragma unroll
            for (int j = 0; j < 4; j++)
                bf[j] = *(const short8*)(&lB[cur][wc * 64 + j * 16 + lm][p]);
            __builtin_amdgcn_s_setprio(1);
#pragma unroll
            for (int i = 0; i < 4; i++)
#pragma unroll
                for (int j = 0; j < 4; j++)
                    acc[i][j] = __builtin_amdgcn_mfma_f32_16x16x32_bf16(
                        af[i], bf[j], acc[i][j], 0, 0, 0);
            __builtin_amdgcn_s_setprio(0);
        }
        asm volatile("s_waitcnt lgkmcnt(0)" ::: "memory");
        __builtin_amdgcn_s_barrier();
        cur ^= 1;
    }
#pragma unroll
    for (int i = 0; i < 4; i++) {
#pragma unroll
        for (int j = 0; j < 4; j++) {
#pragma unroll
            for (int r = 0; r < 4; r++) {
                int m = m0 + wr * 64 + i * 16 + quad * 4 + r;
                int n = n0 + wc * 64 + j * 16 + lm;
                float v = acc[i][j][r];
                if (R) v += R[(size_t)m * N + n];
                C[(size_t)m * N + n] = v;
            }
        }
    }
}

// ---------------- 5. chunked LINEAR scan over half2 cv (4 d's per thread) ----
// phase A: per-chunk composition. grid (CHUNKS, B_), block 256.
__global__ void scanA_k(const __half2* __restrict__ cv, float* __restrict__ Cc,
                        float* __restrict__ Vc) {
    int c = blockIdx.x, b = blockIdx.y, t = threadIdx.x;
    const float4* p = (const float4*)(cv + (size_t)(b * S_ + c * CLEN) * D_) + t;
    float P0 = 1, P1 = 1, P2 = 1, P3 = 1;
    float V0 = 0, V1 = 0, V2 = 0, V3 = 0;
#pragma unroll 4
    for (int s = 0; s < CLEN; s++) {
        float4 raw = p[(size_t)s * (D_ / 4)];
        const __half2* e = (const __half2*)&raw;
        float c0 = __low2float(e[0]), v0 = __high2float(e[0]);
        float c1 = __low2float(e[1]), v1 = __high2float(e[1]);
        float c2 = __low2float(e[2]), v2 = __high2float(e[2]);
        float c3 = __low2float(e[3]), v3 = __high2float(e[3]);
        P0 *= c0; V0 = fmaf(c0, V0, v0);
        P1 *= c1; V1 = fmaf(c1, V1, v1);
        P2 *= c2; V2 = fmaf(c2, V2, v2);
        P3 *= c3; V3 = fmaf(c3, V3, v3);
    }
    size_t q = ((size_t)(b * CHUNKS + c)) * (D_ / 4) + t;
    ((float4*)Cc)[q] = make_float4(P0, P1, P2, P3);
    ((float4*)Vc)[q] = make_float4(V0, V1, V2, V3);
}

// phase C with inline lookback over Cc/Vc (L2-hot). grid (CHUNKS, B_), 256.
__global__ void scanC_k(const __half2* __restrict__ cv, const float* __restrict__ Cc,
                        const float* __restrict__ Vc,
                        __hip_bfloat16* __restrict__ hout, float* __restrict__ ns) {
    int c = blockIdx.x, b = blockIdx.y, t = threadIdx.x;
    float h0 = 0, h1 = 0, h2 = 0, h3 = 0;
#pragma unroll 4
    for (int cc = 0; cc < c; cc++) {
        size_t q = ((size_t)(b * CHUNKS + cc)) * (D_ / 4) + t;
        float4 C4 = ((const float4*)Cc)[q];
        float4 V4 = ((const float4*)Vc)[q];
        h0 = fmaf(C4.x, h0, V4.x); h1 = fmaf(C4.y, h1, V4.y);
        h2 = fmaf(C4.z, h2, V4.z); h3 = fmaf(C4.w, h3, V4.w);
    }
    const float4* p = (const float4*)(cv + (size_t)(b * S_ + c * CLEN) * D_) + t;
    ushort4* hq = (ushort4*)(hout + (size_t)(b * S_ + c * CLEN) * D_) + t;
#pragma unroll 4
    for (int s = 0; s < CLEN; s++) {
        float4 raw = p[(size_t)s * (D_ / 4)];
        const __half2* e = (const __half2*)&raw;
        h0 = fmaf(__low2float(e[0]), h0, __high2float(e[0]));
        h1 = fmaf(__low2float(e[1]), h1, __high2float(e[1]));
        h2 = fmaf(__low2float(e[2]), h2, __high2float(e[2]));
        h3 = fmaf(__low2float(e[3]), h3, __high2float(e[3]));
        ushort4 o;
        o.x = f2bf(h0); o.y = f2bf(h1); o.z = f2bf(h2); o.w = f2bf(h3);
        hq[(size_t)s * (D_ / 4)] = o;
    }
    if (c == CHUNKS - 1)
        ((float4*)(ns + (size_t)b * D_))[t] = make_float4(h0, h1, h2, h3);
}

// ---------------- launcher ----------------
extern "C" void kernel_launch(void* const* d_in, const int* in_sizes, int n_in,
                              void* d_out_v, int out_size, void* d_ws, size_t ws_size,
                              hipStream_t stream) {
    const float* inputs = (const float*)d_in[0];
    const float* nw     = (const float*)d_in[1];
    const float* rw     = (const float*)d_in[2];
    const float* rb     = (const float*)d_in[3];
    const float* whg_e  = (const float*)d_in[4];
    const float* wout_e = (const float*)d_in[5];
    float* out = (float*)d_out_v;

    float* ws = (float*)d_ws;
    __half2*        cv      = (__half2*)ws;                     // 8388608 half2 (33.5 MB)
    __hip_bfloat16* x_bf    = (__hip_bfloat16*)(ws + 8388608);  // 8388608 bf16
    __hip_bfloat16* h_bf    = (__hip_bfloat16*)(ws + 12582912); // 8388608 bf16
    __hip_bfloat16* Whg_bf  = (__hip_bfloat16*)(ws + 16777216); // 8388608 bf16
    __hip_bfloat16* Wout_bf = (__hip_bfloat16*)(ws + 20971520); // 4194304 bf16
    float* xsum  = ws + 23068672;  // 4096
    float* probs = ws + 23072768;  // 32
    float* Cc    = ws + 23072800;  // 262144
    float* Vc    = ws + 23334944;  // 262144

    hipMemsetAsync(xsum, 0, (size_t)B_ * D_ * sizeof(float), stream);

    rmsnorm_k<<<dim3(S_, B_), 256, 0, stream>>>(inputs, nw, x_bf);
    xsum_k<<<dim3(D_ / 256, B_, 16), 256, 0, stream>>>(x_bf, xsum);
    router_k<<<1, 256, 0, stream>>>(xsum, rw, rb, probs,
                                    out + (size_t)B_ * S_ * D_ + (size_t)B_ * D_);
    mix_k<<<3072, 256, 0, stream>>>(probs, whg_e, wout_e, Whg_bf, Wout_bf);

    // fused GEMM1 + (c,v): flattened swizzled grid (256 tiles, B in z)
    gemm_hg_cv<<<dim3(256, 1, B_), 256, 0, stream>>>(x_bf, Whg_bf, cv);

    scanA_k<<<dim3(CHUNKS, B_), 256, 0, stream>>>(cv, Cc, Vc);
    scanC_k<<<dim3(CHUNKS, B_), 256, 0, stream>>>(
        cv, Cc, Vc, h_bf, out + (size_t)B_ * S_ * D_);

    // out[b] = h[b] (2048x1024) * Wout[b]^T + inputs[b]
    gemm_bf16_bt<<<dim3(128, 1, B_), 256, 0, stream>>>(
        h_bf, Wout_bf, out, inputs, S_, D_, D_,
        (size_t)S_ * D_, (size_t)D_ * D_, (size_t)S_ * D_, (size_t)S_ * D_);
}

// Round 4
// 304.431 us; speedup vs baseline: 1.0242x; 1.0132x over previous
//
#include <hip/hip_runtime.h>
#include <hip/hip_bf16.h>
#include <hip/hip_fp16.h>

#define B_  4
#define S_  2048
#define D_  1024
#define E_  8
#define K2_ 2048   // 2*D

#define CHUNKS 64
#define CLEN   32  // CHUNKS*CLEN == S_

typedef __attribute__((ext_vector_type(8))) short short8;   // 8 bf16 (4 VGPRs)
typedef __attribute__((ext_vector_type(4))) float floatx4;  // 4 fp32 acc

__device__ __forceinline__ void gld16(const void* g, const void* l) {
    __builtin_amdgcn_global_load_lds(
        (const __attribute__((address_space(1))) unsigned int*)g,
        (__attribute__((address_space(3))) unsigned int*)l, 16, 0, 0);
}

// float -> bf16 bits (RNE)
__device__ __forceinline__ unsigned short f2bf(float f) {
    unsigned int u = __float_as_uint(f);
    u += 0x7fffu + ((u >> 16) & 1u);
    return (unsigned short)(u >> 16);
}

// ---------------- 1. RMSNorm (f32 in -> bf16 out), vectorized ----------------
__global__ void rmsnorm_k(const float* __restrict__ in, const float* __restrict__ nw,
                          __hip_bfloat16* __restrict__ x) {
    int b = blockIdx.y, s = blockIdx.x, t = threadIdx.x;
    const float4* row = (const float4*)(in + ((size_t)b * S_ + s) * D_);
    float4 v = row[t];
    float ss = v.x * v.x + v.y * v.y + v.z * v.z + v.w * v.w;
#pragma unroll
    for (int o = 32; o > 0; o >>= 1) ss += __shfl_down(ss, o, 64);
    __shared__ float ls[4];
    if ((t & 63) == 0) ls[t >> 6] = ss;
    __syncthreads();
    float tot = ls[0] + ls[1] + ls[2] + ls[3];
    float rs = rsqrtf(tot * (1.0f / (float)D_) + 1e-6f);
    float4 w = ((const float4*)nw)[t];
    ushort4 o;
    o.x = f2bf(v.x * rs * w.x); o.y = f2bf(v.y * rs * w.y);
    o.z = f2bf(v.z * rs * w.z); o.w = f2bf(v.w * rs * w.w);
    ((ushort4*)(x + ((size_t)b * S_ + s) * D_))[t] = o;
}

// ---------------- 2a. column sums of x over S (router mean) ----------------
__global__ void xsum_k(const __hip_bfloat16* __restrict__ x, float* __restrict__ xs) {
    int d = blockIdx.x * 256 + threadIdx.x;
    int b = blockIdx.y;
    int s0 = blockIdx.z * 128;
    const __hip_bfloat16* p = x + ((size_t)b * S_ + s0) * D_ + d;
    float acc = 0.0f;
#pragma unroll 4
    for (int s = 0; s < 128; s++) { acc += __bfloat162float(*p); p += D_; }
    atomicAdd(&xs[b * D_ + d], acc);
}

// ---------------- 2b. router logits + softmax (+ aux_loss=0) ----------------
__global__ void router_k(const float* __restrict__ xs, const float* __restrict__ rw,
                         const float* __restrict__ rb, float* __restrict__ probs,
                         float* __restrict__ aux) {
    int t = threadIdx.x;
    if (t == 255) *aux = 0.0f;
    int pair = t >> 3, sub = t & 7;
    int b = pair >> 3, e = pair & 7;
    float acc = 0.0f;
#pragma unroll 8
    for (int d = sub; d < D_; d += 8) acc += xs[b * D_ + d] * rw[e * D_ + d];
#pragma unroll
    for (int o = 4; o > 0; o >>= 1) acc += __shfl_down(acc, o, 8);
    __shared__ float lg[32];
    if (sub == 0) lg[pair] = acc * (1.0f / (float)S_) + rb[e];
    __syncthreads();
    if (t < 4) {
        float m = -1e30f;
        for (int e2 = 0; e2 < 8; e2++) m = fmaxf(m, lg[t * 8 + e2]);
        float ssum = 0.0f; float ex[8];
        for (int e2 = 0; e2 < 8; e2++) { ex[e2] = expf(lg[t * 8 + e2] - m); ssum += ex[e2]; }
        for (int e2 = 0; e2 < 8; e2++) probs[t * 8 + e2] = ex[e2] / ssum;
    }
}

// ---------------- 3. mix expert weights (float4 loads, bf16x4 stores) --------
__global__ void mix_k(const float* __restrict__ probs, const float* __restrict__ whg_e,
                      const float* __restrict__ wout_e, __hip_bfloat16* __restrict__ Whg,
                      __hip_bfloat16* __restrict__ Wout) {
    __shared__ float P[32];
    int t = threadIdx.x;
    if (t < 32) P[t] = probs[t];
    __syncthreads();
    size_t i4 = (size_t)blockIdx.x * 256 + t;          // float4 index
    const size_t T1q = (size_t)K2_ * D_ / 4;           // 524288
    const size_t T2q = (size_t)D_ * D_ / 4;            // 262144
    float4 a0 = {0,0,0,0}, a1 = {0,0,0,0}, a2 = {0,0,0,0}, a3 = {0,0,0,0};
    if (i4 < T1q) {
        const float4* src = (const float4*)whg_e;
#pragma unroll
        for (int e = 0; e < 8; e++) {
            float4 wv = src[(size_t)e * T1q + i4];
            float p0 = P[e], p1 = P[8 + e], p2 = P[16 + e], p3 = P[24 + e];
            a0.x += p0 * wv.x; a0.y += p0 * wv.y; a0.z += p0 * wv.z; a0.w += p0 * wv.w;
            a1.x += p1 * wv.x; a1.y += p1 * wv.y; a1.z += p1 * wv.z; a1.w += p1 * wv.w;
            a2.x += p2 * wv.x; a2.y += p2 * wv.y; a2.z += p2 * wv.z; a2.w += p2 * wv.w;
            a3.x += p3 * wv.x; a3.y += p3 * wv.y; a3.z += p3 * wv.z; a3.w += p3 * wv.w;
        }
        ushort4* dst = (ushort4*)Whg;
        ushort4 o;
        o.x = f2bf(a0.x); o.y = f2bf(a0.y); o.z = f2bf(a0.z); o.w = f2bf(a0.w);
        dst[0 * T1q + i4] = o;
        o.x = f2bf(a1.x); o.y = f2bf(a1.y); o.z = f2bf(a1.z); o.w = f2bf(a1.w);
        dst[1 * T1q + i4] = o;
        o.x = f2bf(a2.x); o.y = f2bf(a2.y); o.z = f2bf(a2.z); o.w = f2bf(a2.w);
        dst[2 * T1q + i4] = o;
        o.x = f2bf(a3.x); o.y = f2bf(a3.y); o.z = f2bf(a3.z); o.w = f2bf(a3.w);
        dst[3 * T1q + i4] = o;
    } else {
        size_t j4 = i4 - T1q;
        const float4* src = (const float4*)wout_e;
#pragma unroll
        for (int e = 0; e < 8; e++) {
            float4 wv = src[(size_t)e * T2q + j4];
            float p0 = P[e], p1 = P[8 + e], p2 = P[16 + e], p3 = P[24 + e];
            a0.x += p0 * wv.x; a0.y += p0 * wv.y; a0.z += p0 * wv.z; a0.w += p0 * wv.w;
            a1.x += p1 * wv.x; a1.y += p1 * wv.y; a1.z += p1 * wv.z; a1.w += p1 * wv.w;
            a2.x += p2 * wv.x; a2.y += p2 * wv.y; a2.z += p2 * wv.z; a2.w += p2 * wv.w;
            a3.x += p3 * wv.x; a3.y += p3 * wv.y; a3.z += p3 * wv.z; a3.w += p3 * wv.w;
        }
        ushort4* dst = (ushort4*)Wout;
        ushort4 o;
        o.x = f2bf(a0.x); o.y = f2bf(a0.y); o.z = f2bf(a0.z); o.w = f2bf(a0.w);
        dst[0 * T2q + j4] = o;
        o.x = f2bf(a1.x); o.y = f2bf(a1.y); o.z = f2bf(a1.z); o.w = f2bf(a1.w);
        dst[1 * T2q + j4] = o;
        o.x = f2bf(a2.x); o.y = f2bf(a2.y); o.z = f2bf(a2.z); o.w = f2bf(a2.w);
        dst[2 * T2q + j4] = o;
        o.x = f2bf(a3.x); o.y = f2bf(a3.y); o.z = f2bf(a3.z); o.w = f2bf(a3.w);
        dst[3 * T2q + j4] = o;
    }
}

// ---------------- 4. fused GEMM1 + (c,v) epilogue, 256m x 128n-dual tile -----
// Round-8: bigger wave tile (64m x 64n-dual = 12 ds_read -> 32 MFMA, was
// 8 -> 16) to relieve the shared-LDS-pipe oversubscription. 512 threads,
// 8 waves (4m x 2n), LDS 128 KB (1 block/CU = 8 waves, same residency as
// before). Sync structure is R1's proven one: stage -> vmcnt(8) -> barrier ->
// compute -> lgkmcnt(0) -> barrier. Loads/thread still exactly 8.
__global__ __launch_bounds__(512, 2) void gemm_hg_cv(
    const __hip_bfloat16* __restrict__ A, const __hip_bfloat16* __restrict__ Bm,
    __half2* __restrict__ cv) {
    const int K = D_;
    int bz = blockIdx.z;
    A  += (size_t)bz * S_ * D_;
    Bm += (size_t)bz * K2_ * D_;
    __half2* CV = cv + (size_t)bz * S_ * D_;
    // 64 tiles (8m x 8n-dual); XCD-chunk swizzle (64%8==0, bijective)
    int id = blockIdx.x;
    int sw = (id & 7) * 8 + (id >> 3);
    int m0 = (sw >> 3) * 256, n0 = (sw & 7) * 128;
    __shared__ __hip_bfloat16 lA[2][256][64];    // 64 KB
    __shared__ __hip_bfloat16 lBh[2][128][64];   // 32 KB
    __shared__ __hip_bfloat16 lBg[2][128][64];   // 32 KB
    int t = threadIdx.x;
    int w = t >> 6, lane = t & 63;
    int lm = lane & 15, quad = lane >> 4;
    int wr = w >> 1, wc = w & 1;             // wave tile: 64 m x 64 n (dual h/g)
    floatx4 acch[4][4] = {};
    floatx4 accg[4][4] = {};
    int srow = lane >> 3;                    // 0..7
    int swzb = ((lane & 7) ^ srow) * 16;     // swizzled source byte-chunk

    const __hip_bfloat16* Bh = Bm;                    // hidden rows 0..1023
    const __hip_bfloat16* Bg = Bm + (size_t)D_ * K;   // gate rows 1024..2047

    // hoisted global staging pointers (advance +128 B per K-step)
    const char* pA[4]; const char* pBhp[2]; const char* pBgp[2];
#pragma unroll
    for (int it = 0; it < 4; it++)
        pA[it] = (const char*)(A + (size_t)(m0 + (w * 4 + it) * 8 + srow) * K) + swzb;
#pragma unroll
    for (int it = 0; it < 2; it++) {
        pBhp[it] = (const char*)(Bh + (size_t)(n0 + (w * 2 + it) * 8 + srow) * K) + swzb;
        pBgp[it] = (const char*)(Bg + (size_t)(n0 + (w * 2 + it) * 8 + srow) * K) + swzb;
    }

    auto stage = [&](int bb) {
#pragma unroll
        for (int it = 0; it < 4; it++) {
            gld16(pA[it], &lA[bb][(w * 4 + it) * 8][0]);
            pA[it] += 128;
        }
#pragma unroll
        for (int it = 0; it < 2; it++) {
            gld16(pBhp[it], &lBh[bb][(w * 2 + it) * 8][0]); pBhp[it] += 128;
            gld16(pBgp[it], &lBg[bb][(w * 2 + it) * 8][0]); pBgp[it] += 128;
        }
    };

    stage(0);
    int cur = 0;
    for (int k0 = 0; k0 < K; k0 += 64) {
        if (k0 + 64 < K) {
            stage(cur ^ 1);                                   // next tile in flight
            asm volatile("s_waitcnt vmcnt(8)" ::: "memory");  // only tile-t's done
        } else {
            asm volatile("s_waitcnt vmcnt(0)" ::: "memory");
        }
        __builtin_amdgcn_s_barrier();                         // tile t visible
#pragma unroll
        for (int kk = 0; kk < 64; kk += 32) {
            short8 af[4], bh[4], bg[4];
            int p = (((kk >> 3) + quad) ^ (lm & 7)) * 8;
#pragma unroll
            for (int i = 0; i < 4; i++)
                af[i] = *(const short8*)(&lA[cur][wr * 64 + i * 16 + lm][p]);
#pragma unroll
            for (int j = 0; j < 4; j++) {
                bh[j] = *(const short8*)(&lBh[cur][wc * 64 + j * 16 + lm][p]);
                bg[j] = *(const short8*)(&lBg[cur][wc * 64 + j * 16 + lm][p]);
            }
            __builtin_amdgcn_s_setprio(1);
#pragma unroll
            for (int i = 0; i < 4; i++)
#pragma unroll
                for (int j = 0; j < 4; j++) {
                    acch[i][j] = __builtin_amdgcn_mfma_f32_16x16x32_bf16(
                        af[i], bh[j], acch[i][j], 0, 0, 0);
                    accg[i][j] = __builtin_amdgcn_mfma_f32_16x16x32_bf16(
                        af[i], bg[j], accg[i][j], 0, 0, 0);
                }
            __builtin_amdgcn_s_setprio(0);
        }
        asm volatile("s_waitcnt lgkmcnt(0)" ::: "memory");    // buf reads retired
        __builtin_amdgcn_s_barrier();                         // safe to overwrite
        cur ^= 1;
    }
#pragma unroll
    for (int i = 0; i < 4; i++) {
#pragma unroll
        for (int j = 0; j < 4; j++) {
#pragma unroll
            for (int r = 0; r < 4; r++) {
                int m = m0 + wr * 64 + i * 16 + quad * 4 + r;
                int n = n0 + wc * 64 + j * 16 + lm;
                float hid = acch[i][j][r];
                float g   = accg[i][j][r];
                float eg  = expf(g);
                float c   = 1.0f / (1.0f + eg);        // sigmoid(-g)
                float sg  = 1.0f - c;                  // sigmoid(g)
                float gfn = (hid >= 0.0f) ? (hid + 0.5f)
                                          : (1.0f / (1.0f + expf(-hid)));
                CV[(size_t)m * D_ + n] = __floats2half2_rn(c, sg * gfn);
            }
        }
    }
}

// ---------------- 6. bf16 MFMA GEMM, C = A * B^T (+R), XOR-swizzled LDS ----
// R1-proven structure (unchanged this round for clean attribution).
#define TM 128
#define TN 128
#define TBK 64
__global__ __launch_bounds__(256) void gemm_bf16_bt(
    const __hip_bfloat16* __restrict__ A, const __hip_bfloat16* __restrict__ Bm,
    float* __restrict__ C, const float* __restrict__ R,
    int M, int N, int K, size_t sa, size_t sb, size_t sc, size_t sr) {
    int bz = blockIdx.z;
    A += (size_t)bz * sa; Bm += (size_t)bz * sb; C += (size_t)bz * sc;
    if (R) R += (size_t)bz * sr;
    // 128 tiles (16m x 8n): xcd*16 + id/8 (bijective, 128%8==0)
    int id = blockIdx.x;
    int sw = (id & 7) * 16 + (id >> 3);
    int m0 = (sw >> 3) * TM, n0 = (sw & 7) * TN;
    __shared__ __hip_bfloat16 lA[2][TM][TBK];
    __shared__ __hip_bfloat16 lB[2][TN][TBK];
    int t = threadIdx.x;
    int w = t >> 6, lane = t & 63;
    int lm = lane & 15, quad = lane >> 4;
    int wr = w >> 1, wc = w & 1;
    floatx4 acc[4][4] = {};
    int srow = lane >> 3;
    int swzb = ((lane & 7) ^ srow) * 16;

    const char* pA[4]; const char* pB[4];
#pragma unroll
    for (int it = 0; it < 4; it++) {
        pA[it] = (const char*)(A + (size_t)(m0 + (w * 4 + it) * 8 + srow) * K) + swzb;
        pB[it] = (const char*)(Bm + (size_t)(n0 + (w * 4 + it) * 8 + srow) * K) + swzb;
    }

    auto stage = [&](int bb) {
#pragma unroll
        for (int it = 0; it < 4; it++) {
            gld16(pA[it], &lA[bb][(w * 4 + it) * 8][0]); pA[it] += 128;
            gld16(pB[it], &lB[bb][(w * 4 + it) * 8][0]); pB[it] += 128;
        }
    };

    stage(0);
    int cur = 0;
    for (int k0 = 0; k0 < K; k0 += TBK) {
        if (k0 + TBK < K) {
            stage(cur ^ 1);
            asm volatile("s_waitcnt vmcnt(8)" ::: "memory");
        } else {
            asm volatile("s_waitcnt vmcnt(0)" ::: "memory");
        }
        __builtin_amdgcn_s_barrier();
#pragma unroll
        for (int kk = 0; kk < TBK; kk += 32) {
            short8 af[4], bf[4];
            int p = (((kk >> 3) + quad) ^ (lm & 7)) * 8;
#pragma unroll
            for (int i = 0; i < 4; i++)
                af[i] = *(const short8*)(&lA[cur][wr * 64 + i * 16 + lm][p]);
#pragma unroll
            for (int j = 0; j < 4; j++)
                bf[j] = *(const short8*)(&lB[cur][wc * 64 + j * 16 + lm][p]);
            __builtin_amdgcn_s_setprio(1);
#pragma unroll
            for (int i = 0; i < 4; i++)
#pragma unroll
                for (int j = 0; j < 4; j++)
                    acc[i][j] = __builtin_amdgcn_mfma_f32_16x16x32_bf16(
                        af[i], bf[j], acc[i][j], 0, 0, 0);
            __builtin_amdgcn_s_setprio(0);
        }
        asm volatile("s_waitcnt lgkmcnt(0)" ::: "memory");
        __builtin_amdgcn_s_barrier();
        cur ^= 1;
    }
#pragma unroll
    for (int i = 0; i < 4; i++) {
#pragma unroll
        for (int j = 0; j < 4; j++) {
#pragma unroll
            for (int r = 0; r < 4; r++) {
                int m = m0 + wr * 64 + i * 16 + quad * 4 + r;
                int n = n0 + wc * 64 + j * 16 + lm;
                float v = acc[i][j][r];
                if (R) v += R[(size_t)m * N + n];
                C[(size_t)m * N + n] = v;
            }
        }
    }
}

// ---------------- 5. chunked LINEAR scan over half2 cv (4 d's per thread) ----
// phase A: per-chunk composition. grid (CHUNKS, B_), block 256.
__global__ void scanA_k(const __half2* __restrict__ cv, float* __restrict__ Cc,
                        float* __restrict__ Vc) {
    int c = blockIdx.x, b = blockIdx.y, t = threadIdx.x;
    const float4* p = (const float4*)(cv + (size_t)(b * S_ + c * CLEN) * D_) + t;
    float P0 = 1, P1 = 1, P2 = 1, P3 = 1;
    float V0 = 0, V1 = 0, V2 = 0, V3 = 0;
#pragma unroll 4
    for (int s = 0; s < CLEN; s++) {
        float4 raw = p[(size_t)s * (D_ / 4)];
        const __half2* e = (const __half2*)&raw;
        float c0 = __low2float(e[0]), v0 = __high2float(e[0]);
        float c1 = __low2float(e[1]), v1 = __high2float(e[1]);
        float c2 = __low2float(e[2]), v2 = __high2float(e[2]);
        float c3 = __low2float(e[3]), v3 = __high2float(e[3]);
        P0 *= c0; V0 = fmaf(c0, V0, v0);
        P1 *= c1; V1 = fmaf(c1, V1, v1);
        P2 *= c2; V2 = fmaf(c2, V2, v2);
        P3 *= c3; V3 = fmaf(c3, V3, v3);
    }
    size_t q = ((size_t)(b * CHUNKS + c)) * (D_ / 4) + t;
    ((float4*)Cc)[q] = make_float4(P0, P1, P2, P3);
    ((float4*)Vc)[q] = make_float4(V0, V1, V2, V3);
}

// phase C with inline lookback over Cc/Vc (L2-hot). grid (CHUNKS, B_), 256.
__global__ void scanC_k(const __half2* __restrict__ cv, const float* __restrict__ Cc,
                        const float* __restrict__ Vc,
                        __hip_bfloat16* __restrict__ hout, float* __restrict__ ns) {
    int c = blockIdx.x, b = blockIdx.y, t = threadIdx.x;
    float h0 = 0, h1 = 0, h2 = 0, h3 = 0;
#pragma unroll 4
    for (int cc = 0; cc < c; cc++) {
        size_t q = ((size_t)(b * CHUNKS + cc)) * (D_ / 4) + t;
        float4 C4 = ((const float4*)Cc)[q];
        float4 V4 = ((const float4*)Vc)[q];
        h0 = fmaf(C4.x, h0, V4.x); h1 = fmaf(C4.y, h1, V4.y);
        h2 = fmaf(C4.z, h2, V4.z); h3 = fmaf(C4.w, h3, V4.w);
    }
    const float4* p = (const float4*)(cv + (size_t)(b * S_ + c * CLEN) * D_) + t;
    ushort4* hq = (ushort4*)(hout + (size_t)(b * S_ + c * CLEN) * D_) + t;
#pragma unroll 4
    for (int s = 0; s < CLEN; s++) {
        float4 raw = p[(size_t)s * (D_ / 4)];
        const __half2* e = (const __half2*)&raw;
        h0 = fmaf(__low2float(e[0]), h0, __high2float(e[0]));
        h1 = fmaf(__low2float(e[1]), h1, __high2float(e[1]));
        h2 = fmaf(__low2float(e[2]), h2, __high2float(e[2]));
        h3 = fmaf(__low2float(e[3]), h3, __high2float(e[3]));
        ushort4 o;
        o.x = f2bf(h0); o.y = f2bf(h1); o.z = f2bf(h2); o.w = f2bf(h3);
        hq[(size_t)s * (D_ / 4)] = o;
    }
    if (c == CHUNKS - 1)
        ((float4*)(ns + (size_t)b * D_))[t] = make_float4(h0, h1, h2, h3);
}

// ---------------- launcher ----------------
extern "C" void kernel_launch(void* const* d_in, const int* in_sizes, int n_in,
                              void* d_out_v, int out_size, void* d_ws, size_t ws_size,
                              hipStream_t stream) {
    const float* inputs = (const float*)d_in[0];
    const float* nw     = (const float*)d_in[1];
    const float* rw     = (const float*)d_in[2];
    const float* rb     = (const float*)d_in[3];
    const float* whg_e  = (const float*)d_in[4];
    const float* wout_e = (const float*)d_in[5];
    float* out = (float*)d_out_v;

    float* ws = (float*)d_ws;
    __half2*        cv      = (__half2*)ws;                     // 8388608 half2 (33.5 MB)
    __hip_bfloat16* x_bf    = (__hip_bfloat16*)(ws + 8388608);  // 8388608 bf16
    __hip_bfloat16* h_bf    = (__hip_bfloat16*)(ws + 12582912); // 8388608 bf16
    __hip_bfloat16* Whg_bf  = (__hip_bfloat16*)(ws + 16777216); // 8388608 bf16
    __hip_bfloat16* Wout_bf = (__hip_bfloat16*)(ws + 20971520); // 4194304 bf16
    float* xsum  = ws + 23068672;  // 4096
    float* probs = ws + 23072768;  // 32
    float* Cc    = ws + 23072800;  // 262144
    float* Vc    = ws + 23334944;  // 262144

    hipMemsetAsync(xsum, 0, (size_t)B_ * D_ * sizeof(float), stream);

    rmsnorm_k<<<dim3(S_, B_), 256, 0, stream>>>(inputs, nw, x_bf);
    xsum_k<<<dim3(D_ / 256, B_, 16), 256, 0, stream>>>(x_bf, xsum);
    router_k<<<1, 256, 0, stream>>>(xsum, rw, rb, probs,
                                    out + (size_t)B_ * S_ * D_ + (size_t)B_ * D_);
    mix_k<<<3072, 256, 0, stream>>>(probs, whg_e, wout_e, Whg_bf, Wout_bf);

    // fused GEMM1 + (c,v): 256m x 128n-dual tile, 512 threads, 64 tiles x B
    gemm_hg_cv<<<dim3(64, 1, B_), 512, 0, stream>>>(x_bf, Whg_bf, cv);

    scanA_k<<<dim3(CHUNKS, B_), 256, 0, stream>>>(cv, Cc, Vc);
    scanC_k<<<dim3(CHUNKS, B_), 256, 0, stream>>>(
        cv, Cc, Vc, h_bf, out + (size_t)B_ * S_ * D_);

    // out[b] = h[b] (2048x1024) * Wout[b]^T + inputs[b]
    gemm_bf16_bt<<<dim3(128, 1, B_), 256, 0, stream>>>(
        h_bf, Wout_bf, out, inputs, S_, D_, D_,
        (size_t)S_ * D_, (size_t)D_ * D_, (size_t)S_ * D_, (size_t)S_ * D_);
}

// Round 5
// 302.051 us; speedup vs baseline: 1.0323x; 1.0079x over previous
//
#include <hip/hip_runtime.h>
#include <hip/hip_bf16.h>
#include <hip/hip_fp16.h>

#define B_  4
#define S_  2048
#define D_  1024
#define E_  8
#define K2_ 2048   // 2*D

#define CHUNKS 64
#define CLEN   32  // CHUNKS*CLEN == S_

typedef __attribute__((ext_vector_type(8))) short short8;   // 8 bf16 (4 VGPRs)
typedef __attribute__((ext_vector_type(4))) float floatx4;  // 4 fp32 acc

__device__ __forceinline__ void gld16(const void* g, const void* l) {
    __builtin_amdgcn_global_load_lds(
        (const __attribute__((address_space(1))) unsigned int*)g,
        (__attribute__((address_space(3))) unsigned int*)l, 16, 0, 0);
}

// float -> bf16 bits (RNE)
__device__ __forceinline__ unsigned short f2bf(float f) {
    unsigned int u = __float_as_uint(f);
    u += 0x7fffu + ((u >> 16) & 1u);
    return (unsigned short)(u >> 16);
}

// ---------------- 1. RMSNorm (f32 in -> bf16 out), vectorized ----------------
__global__ void rmsnorm_k(const float* __restrict__ in, const float* __restrict__ nw,
                          __hip_bfloat16* __restrict__ x) {
    int b = blockIdx.y, s = blockIdx.x, t = threadIdx.x;
    const float4* row = (const float4*)(in + ((size_t)b * S_ + s) * D_);
    float4 v = row[t];
    float ss = v.x * v.x + v.y * v.y + v.z * v.z + v.w * v.w;
#pragma unroll
    for (int o = 32; o > 0; o >>= 1) ss += __shfl_down(ss, o, 64);
    __shared__ float ls[4];
    if ((t & 63) == 0) ls[t >> 6] = ss;
    __syncthreads();
    float tot = ls[0] + ls[1] + ls[2] + ls[3];
    float rs = rsqrtf(tot * (1.0f / (float)D_) + 1e-6f);
    float4 w = ((const float4*)nw)[t];
    ushort4 o;
    o.x = f2bf(v.x * rs * w.x); o.y = f2bf(v.y * rs * w.y);
    o.z = f2bf(v.z * rs * w.z); o.w = f2bf(v.w * rs * w.w);
    ((ushort4*)(x + ((size_t)b * S_ + s) * D_))[t] = o;
}

// ---------------- 2a. column sums of x over S (router mean) ----------------
__global__ void xsum_k(const __hip_bfloat16* __restrict__ x, float* __restrict__ xs) {
    int d = blockIdx.x * 256 + threadIdx.x;
    int b = blockIdx.y;
    int s0 = blockIdx.z * 128;
    const __hip_bfloat16* p = x + ((size_t)b * S_ + s0) * D_ + d;
    float acc = 0.0f;
#pragma unroll 4
    for (int s = 0; s < 128; s++) { acc += __bfloat162float(*p); p += D_; }
    atomicAdd(&xs[b * D_ + d], acc);
}

// ---------------- 2b. router logits + softmax (+ aux_loss=0) ----------------
__global__ void router_k(const float* __restrict__ xs, const float* __restrict__ rw,
                         const float* __restrict__ rb, float* __restrict__ probs,
                         float* __restrict__ aux) {
    int t = threadIdx.x;
    if (t == 255) *aux = 0.0f;
    int pair = t >> 3, sub = t & 7;
    int b = pair >> 3, e = pair & 7;
    float acc = 0.0f;
#pragma unroll 8
    for (int d = sub; d < D_; d += 8) acc += xs[b * D_ + d] * rw[e * D_ + d];
#pragma unroll
    for (int o = 4; o > 0; o >>= 1) acc += __shfl_down(acc, o, 8);
    __shared__ float lg[32];
    if (sub == 0) lg[pair] = acc * (1.0f / (float)S_) + rb[e];
    __syncthreads();
    if (t < 4) {
        float m = -1e30f;
        for (int e2 = 0; e2 < 8; e2++) m = fmaxf(m, lg[t * 8 + e2]);
        float ssum = 0.0f; float ex[8];
        for (int e2 = 0; e2 < 8; e2++) { ex[e2] = expf(lg[t * 8 + e2] - m); ssum += ex[e2]; }
        for (int e2 = 0; e2 < 8; e2++) probs[t * 8 + e2] = ex[e2] / ssum;
    }
}

// ---------------- 3. mix expert weights (float4 loads, bf16x4 stores) --------
__global__ void mix_k(const float* __restrict__ probs, const float* __restrict__ whg_e,
                      const float* __restrict__ wout_e, __hip_bfloat16* __restrict__ Whg,
                      __hip_bfloat16* __restrict__ Wout) {
    __shared__ float P[32];
    int t = threadIdx.x;
    if (t < 32) P[t] = probs[t];
    __syncthreads();
    size_t i4 = (size_t)blockIdx.x * 256 + t;          // float4 index
    const size_t T1q = (size_t)K2_ * D_ / 4;           // 524288
    const size_t T2q = (size_t)D_ * D_ / 4;            // 262144
    float4 a0 = {0,0,0,0}, a1 = {0,0,0,0}, a2 = {0,0,0,0}, a3 = {0,0,0,0};
    if (i4 < T1q) {
        const float4* src = (const float4*)whg_e;
#pragma unroll
        for (int e = 0; e < 8; e++) {
            float4 wv = src[(size_t)e * T1q + i4];
            float p0 = P[e], p1 = P[8 + e], p2 = P[16 + e], p3 = P[24 + e];
            a0.x += p0 * wv.x; a0.y += p0 * wv.y; a0.z += p0 * wv.z; a0.w += p0 * wv.w;
            a1.x += p1 * wv.x; a1.y += p1 * wv.y; a1.z += p1 * wv.z; a1.w += p1 * wv.w;
            a2.x += p2 * wv.x; a2.y += p2 * wv.y; a2.z += p2 * wv.z; a2.w += p2 * wv.w;
            a3.x += p3 * wv.x; a3.y += p3 * wv.y; a3.z += p3 * wv.z; a3.w += p3 * wv.w;
        }
        ushort4* dst = (ushort4*)Whg;
        ushort4 o;
        o.x = f2bf(a0.x); o.y = f2bf(a0.y); o.z = f2bf(a0.z); o.w = f2bf(a0.w);
        dst[0 * T1q + i4] = o;
        o.x = f2bf(a1.x); o.y = f2bf(a1.y); o.z = f2bf(a1.z); o.w = f2bf(a1.w);
        dst[1 * T1q + i4] = o;
        o.x = f2bf(a2.x); o.y = f2bf(a2.y); o.z = f2bf(a2.z); o.w = f2bf(a2.w);
        dst[2 * T1q + i4] = o;
        o.x = f2bf(a3.x); o.y = f2bf(a3.y); o.z = f2bf(a3.z); o.w = f2bf(a3.w);
        dst[3 * T1q + i4] = o;
    } else {
        size_t j4 = i4 - T1q;
        const float4* src = (const float4*)wout_e;
#pragma unroll
        for (int e = 0; e < 8; e++) {
            float4 wv = src[(size_t)e * T2q + j4];
            float p0 = P[e], p1 = P[8 + e], p2 = P[16 + e], p3 = P[24 + e];
            a0.x += p0 * wv.x; a0.y += p0 * wv.y; a0.z += p0 * wv.z; a0.w += p0 * wv.w;
            a1.x += p1 * wv.x; a1.y += p1 * wv.y; a1.z += p1 * wv.z; a1.w += p1 * wv.w;
            a2.x += p2 * wv.x; a2.y += p2 * wv.y; a2.z += p2 * wv.z; a2.w += p2 * wv.w;
            a3.x += p3 * wv.x; a3.y += p3 * wv.y; a3.z += p3 * wv.z; a3.w += p3 * wv.w;
        }
        ushort4* dst = (ushort4*)Wout;
        ushort4 o;
        o.x = f2bf(a0.x); o.y = f2bf(a0.y); o.z = f2bf(a0.z); o.w = f2bf(a0.w);
        dst[0 * T2q + j4] = o;
        o.x = f2bf(a1.x); o.y = f2bf(a1.y); o.z = f2bf(a1.z); o.w = f2bf(a1.w);
        dst[1 * T2q + j4] = o;
        o.x = f2bf(a2.x); o.y = f2bf(a2.y); o.z = f2bf(a2.z); o.w = f2bf(a2.w);
        dst[2 * T2q + j4] = o;
        o.x = f2bf(a3.x); o.y = f2bf(a3.y); o.z = f2bf(a3.z); o.w = f2bf(a3.w);
        dst[3 * T2q + j4] = o;
    }
}

// ---------------- 4. fused GEMM1 + (c,v) epilogue, 256m x 128n-dual tile -----
// Round-9: 8-phase schedule (T3+T4). Per K-tile: 4 phases, each
// {8 ds_read subtile || stage issue -> barrier -> lgkmcnt(0)+sched_barrier ->
//  setprio(1) -> 16 MFMA -> setprio(0) -> barrier}; vmcnt(0) once per K-tile
// at its top (only this tile's 8 loads are outstanding there — counted
// semantics, never drained mid-pipeline). Stage issue front-loaded into
// phases 0-1 so trailing loads get >=2.5 phases (~1000 cy) of cover.
__global__ __launch_bounds__(512, 2) void gemm_hg_cv(
    const __hip_bfloat16* __restrict__ A, const __hip_bfloat16* __restrict__ Bm,
    __half2* __restrict__ cv) {
    const int K = D_;
    int bz = blockIdx.z;
    A  += (size_t)bz * S_ * D_;
    Bm += (size_t)bz * K2_ * D_;
    __half2* CV = cv + (size_t)bz * S_ * D_;
    // 64 tiles (8m x 8n-dual); XCD-chunk swizzle (64%8==0, bijective)
    int id = blockIdx.x;
    int sw = (id & 7) * 8 + (id >> 3);
    int m0 = (sw >> 3) * 256, n0 = (sw & 7) * 128;
    __shared__ __hip_bfloat16 lA[2][256][64];    // 64 KB
    __shared__ __hip_bfloat16 lBh[2][128][64];   // 32 KB
    __shared__ __hip_bfloat16 lBg[2][128][64];   // 32 KB
    int t = threadIdx.x;
    int w = t >> 6, lane = t & 63;
    int lm = lane & 15, quad = lane >> 4;
    int wr = w >> 1, wc = w & 1;             // wave tile: 64 m x 64 n (dual h/g)
    floatx4 acch[4][4] = {};
    floatx4 accg[4][4] = {};
    int srow = lane >> 3;                    // 0..7
    int swzb = ((lane & 7) ^ srow) * 16;     // swizzled source byte-chunk

    const __hip_bfloat16* Bh = Bm;                    // hidden rows 0..1023
    const __hip_bfloat16* Bg = Bm + (size_t)D_ * K;   // gate rows 1024..2047

    // hoisted global staging pointers (advance +128 B per K-tile)
    const char* pA[4]; const char* pBhp[2]; const char* pBgp[2];
#pragma unroll
    for (int it = 0; it < 4; it++)
        pA[it] = (const char*)(A + (size_t)(m0 + (w * 4 + it) * 8 + srow) * K) + swzb;
#pragma unroll
    for (int it = 0; it < 2; it++) {
        pBhp[it] = (const char*)(Bh + (size_t)(n0 + (w * 2 + it) * 8 + srow) * K) + swzb;
        pBgp[it] = (const char*)(Bg + (size_t)(n0 + (w * 2 + it) * 8 + srow) * K) + swzb;
    }

    // half of a K-tile's staging (4 gld16); part 0 / part 1
    auto stage_part = [&](int bb, int part) {
        if (part == 0) {
            gld16(pA[0], &lA[bb][(w * 4 + 0) * 8][0]); pA[0] += 128;
            gld16(pA[1], &lA[bb][(w * 4 + 1) * 8][0]); pA[1] += 128;
            gld16(pBhp[0], &lBh[bb][(w * 2 + 0) * 8][0]); pBhp[0] += 128;
            gld16(pBgp[0], &lBg[bb][(w * 2 + 0) * 8][0]); pBgp[0] += 128;
        } else {
            gld16(pA[2], &lA[bb][(w * 4 + 2) * 8][0]); pA[2] += 128;
            gld16(pA[3], &lA[bb][(w * 4 + 3) * 8][0]); pA[3] += 128;
            gld16(pBhp[1], &lBh[bb][(w * 2 + 1) * 8][0]); pBhp[1] += 128;
            gld16(pBgp[1], &lBg[bb][(w * 2 + 1) * 8][0]); pBgp[1] += 128;
        }
    };

    stage_part(0, 0); stage_part(0, 1);
    int cur = 0;
    for (int kt = 0; kt < 16; kt++) {
        // only this K-tile's 8 loads are outstanding here
        asm volatile("s_waitcnt vmcnt(0)" ::: "memory");
        __builtin_amdgcn_s_barrier();
        bool pre = (kt < 15);
#pragma unroll
        for (int p = 0; p < 4; p++) {
            const int kh = p & 1, bjh = p >> 1;
            const int off = ((kh * 4 + quad) ^ (lm & 7)) * 16;  // byte offset in row
            short8 af[4], bhf[2], bgf[2];
#pragma unroll
            for (int i = 0; i < 4; i++)
                af[i] = *(const short8*)((const char*)&lA[cur][wr * 64 + i * 16 + lm][0] + off);
#pragma unroll
            for (int jj = 0; jj < 2; jj++) {
                int j = bjh * 2 + jj;
                bhf[jj] = *(const short8*)((const char*)&lBh[cur][wc * 64 + j * 16 + lm][0] + off);
                bgf[jj] = *(const short8*)((const char*)&lBg[cur][wc * 64 + j * 16 + lm][0] + off);
            }
            if (pre && p < 2) stage_part(cur ^ 1, p);   // next tile, front-loaded
            __builtin_amdgcn_s_barrier();
            asm volatile("s_waitcnt lgkmcnt(0)" ::: "memory");
            __builtin_amdgcn_sched_barrier(0);
            __builtin_amdgcn_s_setprio(1);
#pragma unroll
            for (int i = 0; i < 4; i++)
#pragma unroll
                for (int jj = 0; jj < 2; jj++) {
                    int j = bjh * 2 + jj;
                    acch[i][j] = __builtin_amdgcn_mfma_f32_16x16x32_bf16(
                        af[i], bhf[jj], acch[i][j], 0, 0, 0);
                    accg[i][j] = __builtin_amdgcn_mfma_f32_16x16x32_bf16(
                        af[i], bgf[jj], accg[i][j], 0, 0, 0);
                }
            __builtin_amdgcn_s_setprio(0);
            __builtin_amdgcn_s_barrier();
        }
        cur ^= 1;
    }
#pragma unroll
    for (int i = 0; i < 4; i++) {
#pragma unroll
        for (int j = 0; j < 4; j++) {
#pragma unroll
            for (int r = 0; r < 4; r++) {
                int m = m0 + wr * 64 + i * 16 + quad * 4 + r;
                int n = n0 + wc * 64 + j * 16 + lm;
                float hid = acch[i][j][r];
                float g   = accg[i][j][r];
                float eg  = expf(g);
                float c   = 1.0f / (1.0f + eg);        // sigmoid(-g)
                float sg  = 1.0f - c;                  // sigmoid(g)
                float gfn = (hid >= 0.0f) ? (hid + 0.5f)
                                          : (1.0f / (1.0f + expf(-hid)));
                CV[(size_t)m * D_ + n] = __floats2half2_rn(c, sg * gfn);
            }
        }
    }
}

// ---------------- 6. bf16 MFMA GEMM, C = A * B^T (+R), XOR-swizzled LDS ----
// R1-proven 2-phase counted-vmcnt structure (128^2+8ph is documented-negative,
// so this stays). Nontemporal C stores (out never re-read -> no write-RFO).
#define TM 128
#define TN 128
#define TBK 64
__global__ __launch_bounds__(256) void gemm_bf16_bt(
    const __hip_bfloat16* __restrict__ A, const __hip_bfloat16* __restrict__ Bm,
    float* __restrict__ C, const float* __restrict__ R,
    int M, int N, int K, size_t sa, size_t sb, size_t sc, size_t sr) {
    int bz = blockIdx.z;
    A += (size_t)bz * sa; Bm += (size_t)bz * sb; C += (size_t)bz * sc;
    if (R) R += (size_t)bz * sr;
    // 128 tiles (16m x 8n): xcd*16 + id/8 (bijective, 128%8==0)
    int id = blockIdx.x;
    int sw = (id & 7) * 16 + (id >> 3);
    int m0 = (sw >> 3) * TM, n0 = (sw & 7) * TN;
    __shared__ __hip_bfloat16 lA[2][TM][TBK];
    __shared__ __hip_bfloat16 lB[2][TN][TBK];
    int t = threadIdx.x;
    int w = t >> 6, lane = t & 63;
    int lm = lane & 15, quad = lane >> 4;
    int wr = w >> 1, wc = w & 1;
    floatx4 acc[4][4] = {};
    int srow = lane >> 3;
    int swzb = ((lane & 7) ^ srow) * 16;

    const char* pA[4]; const char* pB[4];
#pragma unroll
    for (int it = 0; it < 4; it++) {
        pA[it] = (const char*)(A + (size_t)(m0 + (w * 4 + it) * 8 + srow) * K) + swzb;
        pB[it] = (const char*)(Bm + (size_t)(n0 + (w * 4 + it) * 8 + srow) * K) + swzb;
    }

    auto stage = [&](int bb) {
#pragma unroll
        for (int it = 0; it < 4; it++) {
            gld16(pA[it], &lA[bb][(w * 4 + it) * 8][0]); pA[it] += 128;
            gld16(pB[it], &lB[bb][(w * 4 + it) * 8][0]); pB[it] += 128;
        }
    };

    stage(0);
    int cur = 0;
    for (int k0 = 0; k0 < K; k0 += TBK) {
        if (k0 + TBK < K) {
            stage(cur ^ 1);
            asm volatile("s_waitcnt vmcnt(8)" ::: "memory");
        } else {
            asm volatile("s_waitcnt vmcnt(0)" ::: "memory");
        }
        __builtin_amdgcn_s_barrier();
#pragma unroll
        for (int kk = 0; kk < TBK; kk += 32) {
            short8 af[4], bf[4];
            int p = (((kk >> 3) + quad) ^ (lm & 7)) * 8;
#pragma unroll
            for (int i = 0; i < 4; i++)
                af[i] = *(const short8*)(&lA[cur][wr * 64 + i * 16 + lm][p]);
#pragma unroll
            for (int j = 0; j < 4; j++)
                bf[j] = *(const short8*)(&lB[cur][wc * 64 + j * 16 + lm][p]);
            __builtin_amdgcn_s_setprio(1);
#pragma unroll
            for (int i = 0; i < 4; i++)
#pragma unroll
                for (int j = 0; j < 4; j++)
                    acc[i][j] = __builtin_amdgcn_mfma_f32_16x16x32_bf16(
                        af[i], bf[j], acc[i][j], 0, 0, 0);
            __builtin_amdgcn_s_setprio(0);
        }
        asm volatile("s_waitcnt lgkmcnt(0)" ::: "memory");
        __builtin_amdgcn_s_barrier();
        cur ^= 1;
    }
#pragma unroll
    for (int i = 0; i < 4; i++) {
#pragma unroll
        for (int j = 0; j < 4; j++) {
#pragma unroll
            for (int r = 0; r < 4; r++) {
                int m = m0 + wr * 64 + i * 16 + quad * 4 + r;
                int n = n0 + wc * 64 + j * 16 + lm;
                float v = acc[i][j][r];
                if (R) v += R[(size_t)m * N + n];
                __builtin_nontemporal_store(v, &C[(size_t)m * N + n]);
            }
        }
    }
}

// ---------------- 5. chunked LINEAR scan over half2 cv (4 d's per thread) ----
// phase A: per-chunk composition. grid (CHUNKS, B_), block 256.
__global__ void scanA_k(const __half2* __restrict__ cv, float* __restrict__ Cc,
                        float* __restrict__ Vc) {
    int c = blockIdx.x, b = blockIdx.y, t = threadIdx.x;
    const float4* p = (const float4*)(cv + (size_t)(b * S_ + c * CLEN) * D_) + t;
    float P0 = 1, P1 = 1, P2 = 1, P3 = 1;
    float V0 = 0, V1 = 0, V2 = 0, V3 = 0;
#pragma unroll 4
    for (int s = 0; s < CLEN; s++) {
        float4 raw = p[(size_t)s * (D_ / 4)];
        const __half2* e = (const __half2*)&raw;
        float c0 = __low2float(e[0]), v0 = __high2float(e[0]);
        float c1 = __low2float(e[1]), v1 = __high2float(e[1]);
        float c2 = __low2float(e[2]), v2 = __high2float(e[2]);
        float c3 = __low2float(e[3]), v3 = __high2float(e[3]);
        P0 *= c0; V0 = fmaf(c0, V0, v0);
        P1 *= c1; V1 = fmaf(c1, V1, v1);
        P2 *= c2; V2 = fmaf(c2, V2, v2);
        P3 *= c3; V3 = fmaf(c3, V3, v3);
    }
    size_t q = ((size_t)(b * CHUNKS + c)) * (D_ / 4) + t;
    ((float4*)Cc)[q] = make_float4(P0, P1, P2, P3);
    ((float4*)Vc)[q] = make_float4(V0, V1, V2, V3);
}

// phase C with inline lookback over Cc/Vc (L2-hot). grid (CHUNKS, B_), 256.
__global__ void scanC_k(const __half2* __restrict__ cv, const float* __restrict__ Cc,
                        const float* __restrict__ Vc,
                        __hip_bfloat16* __restrict__ hout, float* __restrict__ ns) {
    int c = blockIdx.x, b = blockIdx.y, t = threadIdx.x;
    float h0 = 0, h1 = 0, h2 = 0, h3 = 0;
#pragma unroll 4
    for (int cc = 0; cc < c; cc++) {
        size_t q = ((size_t)(b * CHUNKS + cc)) * (D_ / 4) + t;
        float4 C4 = ((const float4*)Cc)[q];
        float4 V4 = ((const float4*)Vc)[q];
        h0 = fmaf(C4.x, h0, V4.x); h1 = fmaf(C4.y, h1, V4.y);
        h2 = fmaf(C4.z, h2, V4.z); h3 = fmaf(C4.w, h3, V4.w);
    }
    const float4* p = (const float4*)(cv + (size_t)(b * S_ + c * CLEN) * D_) + t;
    ushort4* hq = (ushort4*)(hout + (size_t)(b * S_ + c * CLEN) * D_) + t;
#pragma unroll 4
    for (int s = 0; s < CLEN; s++) {
        float4 raw = p[(size_t)s * (D_ / 4)];
        const __half2* e = (const __half2*)&raw;
        h0 = fmaf(__low2float(e[0]), h0, __high2float(e[0]));
        h1 = fmaf(__low2float(e[1]), h1, __high2float(e[1]));
        h2 = fmaf(__low2float(e[2]), h2, __high2float(e[2]));
        h3 = fmaf(__low2float(e[3]), h3, __high2float(e[3]));
        ushort4 o;
        o.x = f2bf(h0); o.y = f2bf(h1); o.z = f2bf(h2); o.w = f2bf(h3);
        hq[(size_t)s * (D_ / 4)] = o;
    }
    if (c == CHUNKS - 1)
        ((float4*)(ns + (size_t)b * D_))[t] = make_float4(h0, h1, h2, h3);
}

// ---------------- launcher ----------------
extern "C" void kernel_launch(void* const* d_in, const int* in_sizes, int n_in,
                              void* d_out_v, int out_size, void* d_ws, size_t ws_size,
                              hipStream_t stream) {
    const float* inputs = (const float*)d_in[0];
    const float* nw     = (const float*)d_in[1];
    const float* rw     = (const float*)d_in[2];
    const float* rb     = (const float*)d_in[3];
    const float* whg_e  = (const float*)d_in[4];
    const float* wout_e = (const float*)d_in[5];
    float* out = (float*)d_out_v;

    float* ws = (float*)d_ws;
    __half2*        cv      = (__half2*)ws;                     // 8388608 half2 (33.5 MB)
    __hip_bfloat16* x_bf    = (__hip_bfloat16*)(ws + 8388608);  // 8388608 bf16
    __hip_bfloat16* h_bf    = (__hip_bfloat16*)(ws + 12582912); // 8388608 bf16
    __hip_bfloat16* Whg_bf  = (__hip_bfloat16*)(ws + 16777216); // 8388608 bf16
    __hip_bfloat16* Wout_bf = (__hip_bfloat16*)(ws + 20971520); // 4194304 bf16
    float* xsum  = ws + 23068672;  // 4096
    float* probs = ws + 23072768;  // 32
    float* Cc    = ws + 23072800;  // 262144
    float* Vc    = ws + 23334944;  // 262144

    hipMemsetAsync(xsum, 0, (size_t)B_ * D_ * sizeof(float), stream);

    rmsnorm_k<<<dim3(S_, B_), 256, 0, stream>>>(inputs, nw, x_bf);
    xsum_k<<<dim3(D_ / 256, B_, 16), 256, 0, stream>>>(x_bf, xsum);
    router_k<<<1, 256, 0, stream>>>(xsum, rw, rb, probs,
                                    out + (size_t)B_ * S_ * D_ + (size_t)B_ * D_);
    mix_k<<<3072, 256, 0, stream>>>(probs, whg_e, wout_e, Whg_bf, Wout_bf);

    // fused GEMM1 + (c,v): 256m x 128n-dual tile, 512 threads, 8-phase
    gemm_hg_cv<<<dim3(64, 1, B_), 512, 0, stream>>>(x_bf, Whg_bf, cv);

    scanA_k<<<dim3(CHUNKS, B_), 256, 0, stream>>>(cv, Cc, Vc);
    scanC_k<<<dim3(CHUNKS, B_), 256, 0, stream>>>(
        cv, Cc, Vc, h_bf, out + (size_t)B_ * S_ * D_);

    // out[b] = h[b] (2048x1024) * Wout[b]^T + inputs[b]
    gemm_bf16_bt<<<dim3(128, 1, B_), 256, 0, stream>>>(
        h_bf, Wout_bf, out, inputs, S_, D_, D_,
        (size_t)S_ * D_, (size_t)D_ * D_, (size_t)S_ * D_, (size_t)S_ * D_);
}